// Round 1
// baseline (1754.416 us; speedup 1.0000x reference)
//
#include <hip/hip_runtime.h>
#include <hip/hip_bf16.h>

#define TT 16
#define NTOK 87040  // 16*8*8*85

// ---------------- fc + window partition ----------------
__global__ __launch_bounds__(128) void fc_part_kernel(
    const float* __restrict__ x, const float* __restrict__ W,
    const float* __restrict__ bias, float* __restrict__ X,
    int CHin, int ws, int tokOff) {
  int tid = threadIdx.x;
  int wsq = ws * ws, HS = 8 * ws;
  long g0 = (long)blockIdx.x * TT;
  __shared__ __align__(16) float a[TT][128];
  float acc[TT];
#pragma unroll
  for (int t = 0; t < TT; t++) acc[t] = 0.f;
  int nk = CHin >> 7;
  for (int kc = 0; kc < nk; kc++) {
    __syncthreads();
#pragma unroll 4
    for (int t = 0; t < TT; t++) {
      long g = g0 + t;
      int tt = (int)(g % wsq);
      long r = g / wsq;
      int bj = (int)(r & 7); r >>= 3;
      int bi = (int)(r & 7); int b = (int)(r >> 3);
      int h = bi * ws + tt / ws, w = bj * ws + tt % ws;
      a[t][tid] = x[((size_t)((b * HS + h) * HS) + w) * CHin + (kc << 7) + tid];
    }
    __syncthreads();
    for (int k4 = 0; k4 < 128; k4 += 4) {
      float wv[4];
#pragma unroll
      for (int kk = 0; kk < 4; kk++) wv[kk] = W[(size_t)((kc << 7) + k4 + kk) * 128 + tid];
#pragma unroll
      for (int t = 0; t < TT; t++) {
        float4 av = *(const float4*)&a[t][k4];
        acc[t] += av.x * wv[0] + av.y * wv[1] + av.z * wv[2] + av.w * wv[3];
      }
    }
  }
  float bb = bias[tid];
#pragma unroll
  for (int t = 0; t < TT; t++) {
    long g = g0 + t;
    int tt = (int)(g % wsq);
    long r = g / wsq;
    int bj = (int)(r & 7); r >>= 3;
    int bi = (int)(r & 7); int b = (int)(r >> 3);
    size_t tok = ((size_t)(((b * 8 + bi) * 8 + bj))) * 85 + tokOff + tt;
    X[tok * 128 + tid] = acc[t] + bb;
  }
}

// ---------------- LayerNorm (one token per block) ----------------
__global__ __launch_bounds__(128) void ln_kernel(
    const float* __restrict__ X, const float* __restrict__ g,
    const float* __restrict__ b, float* __restrict__ out) {
  int tok = blockIdx.x, tid = threadIdx.x;
  __shared__ float red[128];
  float v = X[(size_t)tok * 128 + tid];
  red[tid] = v;
  __syncthreads();
#pragma unroll
  for (int s = 64; s > 0; s >>= 1) {
    if (tid < s) red[tid] += red[tid + s];
    __syncthreads();
  }
  float mean = red[0] * (1.f / 128.f);
  __syncthreads();
  float d = v - mean;
  red[tid] = d * d;
  __syncthreads();
#pragma unroll
  for (int s = 64; s > 0; s >>= 1) {
    if (tid < s) red[tid] += red[tid + s];
    __syncthreads();
  }
  float var = red[0] * (1.f / 128.f);
  out[(size_t)tok * 128 + tid] = d * rsqrtf(var + 1e-6f) * g[tid] + b[tid];
}

// ---------------- QKV projection (128 -> 384) ----------------
__global__ __launch_bounds__(128) void qkv_kernel(
    const float* __restrict__ LN, const float* __restrict__ W, float* __restrict__ QKV) {
  int tid = threadIdx.x;
  size_t tok0 = (size_t)blockIdx.x * TT;
  __shared__ __align__(16) float a[TT][128];
#pragma unroll 4
  for (int t = 0; t < TT; t++) a[t][tid] = LN[(tok0 + t) * 128 + tid];
  __syncthreads();
  float acc0[TT], acc1[TT], acc2[TT];
#pragma unroll
  for (int t = 0; t < TT; t++) { acc0[t] = 0.f; acc1[t] = 0.f; acc2[t] = 0.f; }
  for (int k4 = 0; k4 < 128; k4 += 4) {
    float w0[4], w1[4], w2[4];
#pragma unroll
    for (int kk = 0; kk < 4; kk++) {
      const float* wr = W + (size_t)(k4 + kk) * 384;
      w0[kk] = wr[tid]; w1[kk] = wr[128 + tid]; w2[kk] = wr[256 + tid];
    }
#pragma unroll
    for (int t = 0; t < TT; t++) {
      float4 av = *(const float4*)&a[t][k4];
      acc0[t] += av.x * w0[0] + av.y * w0[1] + av.z * w0[2] + av.w * w0[3];
      acc1[t] += av.x * w1[0] + av.y * w1[1] + av.z * w1[2] + av.w * w1[3];
      acc2[t] += av.x * w2[0] + av.y * w2[1] + av.z * w2[2] + av.w * w2[3];
    }
  }
#pragma unroll 4
  for (int t = 0; t < TT; t++) {
    float* o = QKV + (tok0 + t) * 384;
    o[tid] = acc0[t]; o[128 + tid] = acc1[t]; o[256 + tid] = acc2[t];
  }
}

// ---------------- attention: one (spatial block, head) per CTA ----------------
__global__ __launch_bounds__(256) void attn_kernel(
    const float* __restrict__ QKV, float* __restrict__ AT) {
  int blk = blockIdx.x;
  int h = blk & 7;
  int sb = blk >> 3;
  size_t tok0 = (size_t)sb * 85;
  __shared__ float q[85 * 16];
  __shared__ float kT[16 * 85];
  __shared__ float vT[16 * 85];
  __shared__ float att[85 * 85];
  const float* base = QKV + tok0 * 384;
  for (int e = threadIdx.x; e < 85 * 16; e += 256) {
    int n = e >> 4, d = e & 15;
    q[e] = base[n * 384 + h * 16 + d];
    kT[d * 85 + n] = base[n * 384 + 128 + h * 16 + d];
    vT[d * 85 + n] = base[n * 384 + 256 + h * 16 + d];
  }
  __syncthreads();
  for (int e = threadIdx.x; e < 85 * 85; e += 256) {
    int n = e / 85, m = e - n * 85;
    float s = 0.f;
#pragma unroll
    for (int d = 0; d < 16; d++) s += q[n * 16 + d] * kT[d * 85 + m];
    att[e] = s;
  }
  __syncthreads();
  if (threadIdx.x < 85) {
    float* row = att + threadIdx.x * 85;
    float mx = row[0];
    for (int m = 1; m < 85; m++) mx = fmaxf(mx, row[m]);
    float sum = 0.f;
    for (int m = 0; m < 85; m++) { float e_ = __expf(row[m] - mx); row[m] = e_; sum += e_; }
    float inv = 1.f / sum;
    for (int m = 0; m < 85; m++) row[m] *= inv;
  }
  __syncthreads();
  for (int e = threadIdx.x; e < 85 * 16; e += 256) {
    int n = e >> 4, d = e & 15;
    const float* ar = att + n * 85;
    const float* vr = vT + d * 85;
    float s = 0.f;
    for (int m = 0; m < 85; m++) s += ar[m] * vr[m];
    AT[(tok0 + n) * 128 + h * 16 + d] = s;
  }
}

// ---------------- proj + residual add into X ----------------
__global__ __launch_bounds__(128) void proj_kernel(
    const float* __restrict__ AT, const float* __restrict__ W, float* __restrict__ X) {
  int tid = threadIdx.x;
  size_t tok0 = (size_t)blockIdx.x * TT;
  __shared__ __align__(16) float a[TT][128];
#pragma unroll 4
  for (int t = 0; t < TT; t++) a[t][tid] = AT[(tok0 + t) * 128 + tid];
  __syncthreads();
  float acc[TT];
#pragma unroll
  for (int t = 0; t < TT; t++) acc[t] = 0.f;
  for (int k4 = 0; k4 < 128; k4 += 4) {
    float wv[4];
#pragma unroll
    for (int kk = 0; kk < 4; kk++) wv[kk] = W[(size_t)(k4 + kk) * 128 + tid];
#pragma unroll
    for (int t = 0; t < TT; t++) {
      float4 av = *(const float4*)&a[t][k4];
      acc[t] += av.x * wv[0] + av.y * wv[1] + av.z * wv[2] + av.w * wv[3];
    }
  }
#pragma unroll 4
  for (int t = 0; t < TT; t++) {
    size_t i = (tok0 + t) * 128 + tid;
    X[i] += acc[t];
  }
}

// ---------------- fused MLP: relu(ln @ W1 + b1) @ W2 + b2 + residual ----------------
__global__ __launch_bounds__(128) void ff_kernel(
    const float* __restrict__ LN2, const float* __restrict__ W1, const float* __restrict__ b1,
    const float* __restrict__ W2, const float* __restrict__ b2, float* __restrict__ X) {
  int tid = threadIdx.x;
  size_t tok0 = (size_t)blockIdx.x * TT;
  __shared__ __align__(16) float a[TT][128];
  __shared__ __align__(16) float hid[TT][512];
#pragma unroll 4
  for (int t = 0; t < TT; t++) a[t][tid] = LN2[(tok0 + t) * 128 + tid];
  __syncthreads();
  {
    float acc[4][TT];
#pragma unroll
    for (int g = 0; g < 4; g++)
#pragma unroll
      for (int t = 0; t < TT; t++) acc[g][t] = 0.f;
    for (int k4 = 0; k4 < 128; k4 += 4) {
      float wv[4][4];
#pragma unroll
      for (int kk = 0; kk < 4; kk++)
#pragma unroll
        for (int g = 0; g < 4; g++) wv[kk][g] = W1[(size_t)(k4 + kk) * 512 + g * 128 + tid];
#pragma unroll
      for (int t = 0; t < TT; t++) {
        float4 av = *(const float4*)&a[t][k4];
        float ax[4] = {av.x, av.y, av.z, av.w};
#pragma unroll
        for (int kk = 0; kk < 4; kk++)
#pragma unroll
          for (int g = 0; g < 4; g++) acc[g][t] += ax[kk] * wv[kk][g];
      }
    }
#pragma unroll
    for (int g = 0; g < 4; g++) {
      float bb = b1[g * 128 + tid];
#pragma unroll
      for (int t = 0; t < TT; t++) hid[t][g * 128 + tid] = fmaxf(acc[g][t] + bb, 0.f);
    }
  }
  __syncthreads();
  float acc[TT];
#pragma unroll
  for (int t = 0; t < TT; t++) acc[t] = 0.f;
  for (int k4 = 0; k4 < 512; k4 += 4) {
    float wv[4];
#pragma unroll
    for (int kk = 0; kk < 4; kk++) wv[kk] = W2[(size_t)(k4 + kk) * 128 + tid];
#pragma unroll
    for (int t = 0; t < TT; t++) {
      float4 av = *(const float4*)&hid[t][k4];
      acc[t] += av.x * wv[0] + av.y * wv[1] + av.z * wv[2] + av.w * wv[3];
    }
  }
  float bb = b2[tid];
#pragma unroll 4
  for (int t = 0; t < TT; t++) {
    size_t i = (tok0 + t) * 128 + tid;
    X[i] += acc[t] + bb;
  }
}

// ---------------- un-partition + reverse projection ----------------
__global__ __launch_bounds__(128) void rev_kernel(
    const float* __restrict__ X, const float* __restrict__ W, const float* __restrict__ bias,
    float* __restrict__ out, int CHout, int ws, int tokOff) {
  int tid = threadIdx.x;
  int HS = 8 * ws;
  long p0 = (long)blockIdx.x * TT;
  __shared__ __align__(16) float a[TT][128];
#pragma unroll 4
  for (int t = 0; t < TT; t++) {
    long p = p0 + t;
    int w_ = (int)(p % HS);
    long r = p / HS;
    int hh = (int)(r % HS);
    int b = (int)(r / HS);
    int bi = hh / ws, bj = w_ / ws;
    int tt = (hh % ws) * ws + (w_ % ws);
    size_t tok = ((size_t)((b * 8 + bi) * 8 + bj)) * 85 + tokOff + tt;
    a[t][tid] = X[tok * 128 + tid];
  }
  __syncthreads();
  int ng = CHout >> 7;
  for (int g = 0; g < ng; g++) {
    int c = (g << 7) + tid;
    float acc[TT];
#pragma unroll
    for (int t = 0; t < TT; t++) acc[t] = 0.f;
    for (int k4 = 0; k4 < 128; k4 += 4) {
      float wv[4];
#pragma unroll
      for (int kk = 0; kk < 4; kk++) wv[kk] = W[(size_t)(k4 + kk) * CHout + c];
#pragma unroll
      for (int t = 0; t < TT; t++) {
        float4 av = *(const float4*)&a[t][k4];
        acc[t] += av.x * wv[0] + av.y * wv[1] + av.z * wv[2] + av.w * wv[3];
      }
    }
    float bb = bias[c];
#pragma unroll 4
    for (int t = 0; t < TT; t++) out[(size_t)(p0 + t) * CHout + c] = acc[t] + bb;
  }
}

extern "C" void kernel_launch(void* const* d_in, const int* in_sizes, int n_in,
                              void* d_out, int out_size, void* d_ws, size_t ws_size,
                              hipStream_t stream) {
  // setup_inputs dict order: per j: x, fcW, fcb, revW, revb; then ln1g, ln1b,
  // ln2g, ln2b, qkvW, projW, fc1W, fc1b, fc2W, fc2b
  const float* x[4]; const float* fcW[4]; const float* fcb[4];
  const float* revW[4]; const float* revb[4];
  for (int j = 0; j < 4; j++) {
    x[j]    = (const float*)d_in[j * 5 + 0];
    fcW[j]  = (const float*)d_in[j * 5 + 1];
    fcb[j]  = (const float*)d_in[j * 5 + 2];
    revW[j] = (const float*)d_in[j * 5 + 3];
    revb[j] = (const float*)d_in[j * 5 + 4];
  }
  const float* ln1g = (const float*)d_in[20];
  const float* ln1b = (const float*)d_in[21];
  const float* ln2g = (const float*)d_in[22];
  const float* ln2b = (const float*)d_in[23];
  const float* qkvW = (const float*)d_in[24];
  const float* projW = (const float*)d_in[25];
  const float* fc1W = (const float*)d_in[26];
  const float* fc1b = (const float*)d_in[27];
  const float* fc2W = (const float*)d_in[28];
  const float* fc2b = (const float*)d_in[29];

  float* X   = (float*)d_ws;                       // 87040*128
  float* QKV = X + (size_t)NTOK * 128;             // 87040*384
  float* TMP = QKV + (size_t)NTOK * 384;           // 87040*128 (LN out / attn out)

  static const int wsArr[4] = {8, 4, 2, 1};
  static const int CH[4] = {128, 256, 512, 1024};
  static const int tokOff[4] = {0, 64, 80, 84};

  for (int j = 0; j < 4; j++) {
    int HS = 8 * wsArr[j];
    int rows = 16 * HS * HS;
    fc_part_kernel<<<rows / TT, 128, 0, stream>>>(x[j], fcW[j], fcb[j], X, CH[j], wsArr[j], tokOff[j]);
  }
  ln_kernel<<<NTOK, 128, 0, stream>>>(X, ln1g, ln1b, TMP);
  qkv_kernel<<<NTOK / TT, 128, 0, stream>>>(TMP, qkvW, QKV);
  attn_kernel<<<1024 * 8, 256, 0, stream>>>(QKV, TMP);
  proj_kernel<<<NTOK / TT, 128, 0, stream>>>(TMP, projW, X);
  ln_kernel<<<NTOK, 128, 0, stream>>>(X, ln2g, ln2b, TMP);
  ff_kernel<<<NTOK / TT, 128, 0, stream>>>(TMP, fc1W, fc1b, fc2W, fc2b, X);

  float* out = (float*)d_out;
  size_t outOff = 0;
  for (int j = 0; j < 4; j++) {
    int HS = 8 * wsArr[j];
    int rows = 16 * HS * HS;
    rev_kernel<<<rows / TT, 128, 0, stream>>>(X, revW[j], revb[j], out + outOff, CH[j], wsArr[j], tokOff[j]);
    outOff += (size_t)rows * CH[j];
  }
}

// Round 2
// 850.861 us; speedup vs baseline: 2.0619x; 2.0619x over previous
//
#include <hip/hip_runtime.h>
#include <hip/hip_bf16.h>

#define NTOK 87040  // 1024 windows * 85 tokens

typedef __attribute__((ext_vector_type(8))) short bf16x8;
typedef __attribute__((ext_vector_type(4))) float f32x4;

#define MFMA __builtin_amdgcn_mfma_f32_16x16x32_bf16

__device__ __forceinline__ unsigned short f2b(float f) {
  unsigned int u; __builtin_memcpy(&u, &f, 4);
  u += 0x7fffu + ((u >> 16) & 1u);  // RNE
  return (unsigned short)(u >> 16);
}
__device__ __forceinline__ float b2f(short s) {
  unsigned int u = ((unsigned int)(unsigned short)s) << 16;
  float f; __builtin_memcpy(&f, &u, 4);
  return f;
}
__device__ __forceinline__ bf16x8 ldg8(const short* p) { return *(const bf16x8*)p; }

// natural spatial row p -> window token index
__device__ __forceinline__ int tokmap(int p, int hsShift, int wsShift, int tokOff) {
  int HSm = (1 << hsShift) - 1;
  int w = p & HSm;
  int h = (p >> hsShift) & HSm;
  int b = p >> (2 * hsShift);
  int bi = h >> wsShift, bj = w >> wsShift;
  int wsm = (1 << wsShift) - 1;
  int tt = ((h & wsm) << wsShift) + (w & wsm);
  return ((((b << 3) | bi) << 3) | bj) * 85 + tokOff + tt;
}

// ---------------- input fp32 -> bf16 ----------------
struct CvtX {
  const float* src[4];
  short* dst[4];
  int off[5];  // element offsets
};
__global__ __launch_bounds__(256) void cvt_x_kernel(CvtX p) {
  int e = (blockIdx.x * 256 + threadIdx.x) * 4;
  int s = 0;
#pragma unroll
  for (int t = 0; t < 4; t++) if (e >= p.off[t + 1]) s = t + 1;
  if (s >= 4) return;
  int local = e - p.off[s];
  float4 v = *(const float4*)(p.src[s] + local);
  unsigned int lo = ((unsigned int)f2b(v.y) << 16) | f2b(v.x);
  unsigned int hi = ((unsigned int)f2b(v.w) << 16) | f2b(v.z);
  uint2 o; o.x = lo; o.y = hi;
  *(uint2*)(p.dst[s] + local) = o;
}

// ---------------- weights: fp32 [K][N] -> bf16 [N][K] ----------------
struct PrepW {
  const float* src[12];
  short* dst[12];
  int kshift[12];
  int N[12];
  int off[13];
};
__global__ __launch_bounds__(256) void prep_w_kernel(PrepW p) {
  int i = blockIdx.x * 256 + threadIdx.x;
  int s = 0;
#pragma unroll
  for (int t = 0; t < 12; t++) if (i >= p.off[t + 1]) s = t + 1;
  if (s >= 12) return;
  int e = i - p.off[s];
  int K = 1 << p.kshift[s];
  int n = e >> p.kshift[s];
  int k = e & (K - 1);
  p.dst[s][e] = (short)f2b(p.src[s][(size_t)k * p.N[s] + n]);
}

// ---------------- fc + window partition (MFMA) ----------------
// A = XIN bf16 [rows][CH] natural order, Wt bf16 [128][CH], out scatter to X f32
template <int CH>
__global__ __launch_bounds__(256) void fc_mfma(
    const short* __restrict__ XIN, const short* __restrict__ Wt,
    const float* __restrict__ bias, float* __restrict__ X,
    int hsShift, int wsShift, int tokOff) {
  int wid = threadIdx.x >> 6, lane = threadIdx.x & 63;
  int col15 = lane & 15, kg = lane >> 4;
  int p0 = blockIdx.x * 64 + wid * 16;
  const short* abase = XIN + (size_t)(p0 + col15) * CH + kg * 8;
  f32x4 c[8];
#pragma unroll
  for (int nt = 0; nt < 8; nt++) c[nt] = (f32x4){0.f, 0.f, 0.f, 0.f};
  for (int ks = 0; ks < CH / 32; ks++) {
    bf16x8 a = ldg8(abase + ks * 32);
#pragma unroll
    for (int nt = 0; nt < 8; nt++) {
      bf16x8 b = ldg8(Wt + (size_t)(nt * 16 + col15) * CH + ks * 32 + kg * 8);
      c[nt] = MFMA(a, b, c[nt], 0, 0, 0);
    }
  }
  size_t obase[4];
#pragma unroll
  for (int r = 0; r < 4; r++)
    obase[r] = (size_t)tokmap(p0 + kg * 4 + r, hsShift, wsShift, tokOff) * 128;
#pragma unroll
  for (int nt = 0; nt < 8; nt++) {
    int col = nt * 16 + col15;
    float bb = bias[col];
#pragma unroll
    for (int r = 0; r < 4; r++) X[obase[r] + col] = c[nt][r] + bb;
  }
}

// ---------------- LayerNorm: one wave per token, bf16 out ----------------
__global__ __launch_bounds__(256) void ln_kernel(
    const float* __restrict__ X, const float* __restrict__ g,
    const float* __restrict__ b, short* __restrict__ out) {
  int wid = threadIdx.x >> 6, lane = threadIdx.x & 63;
  size_t tok = (size_t)blockIdx.x * 4 + wid;
  float2 v = *(const float2*)(X + tok * 128 + lane * 2);
  float s = v.x + v.y;
#pragma unroll
  for (int off = 32; off > 0; off >>= 1) s += __shfl_xor(s, off);
  float mean = s * (1.f / 128.f);
  float dx = v.x - mean, dy = v.y - mean;
  float q = dx * dx + dy * dy;
#pragma unroll
  for (int off = 32; off > 0; off >>= 1) q += __shfl_xor(q, off);
  float inv = rsqrtf(q * (1.f / 128.f) + 1e-6f);
  float2 gg = *(const float2*)(g + lane * 2);
  float2 bb = *(const float2*)(b + lane * 2);
  float o0 = dx * inv * gg.x + bb.x;
  float o1 = dy * inv * gg.y + bb.y;
  unsigned int pk = ((unsigned int)f2b(o1) << 16) | f2b(o0);
  *(unsigned int*)(out + tok * 128 + lane * 2) = pk;
}

// ---------------- QKV (K=128, N=384) ----------------
__global__ __launch_bounds__(256) void qkv_mfma(
    const short* __restrict__ XB, const short* __restrict__ Wt,
    short* __restrict__ QKVB) {
  int wid = threadIdx.x >> 6, lane = threadIdx.x & 63;
  int col15 = lane & 15, kg = lane >> 4;
  size_t tok0 = (size_t)blockIdx.x * 64 + wid * 16;
  const short* abase = XB + (tok0 + col15) * 128 + kg * 8;
  bf16x8 a[4];
#pragma unroll
  for (int ks = 0; ks < 4; ks++) a[ks] = ldg8(abase + ks * 32);
  size_t orow[4];
#pragma unroll
  for (int r = 0; r < 4; r++) orow[r] = (tok0 + kg * 4 + r) * 384;
  for (int nt = 0; nt < 24; nt++) {
    const short* bbase = Wt + (size_t)(nt * 16 + col15) * 128 + kg * 8;
    f32x4 c = (f32x4){0.f, 0.f, 0.f, 0.f};
#pragma unroll
    for (int ks = 0; ks < 4; ks++) c = MFMA(a[ks], ldg8(bbase + ks * 32), c, 0, 0, 0);
    int col = nt * 16 + col15;
#pragma unroll
    for (int r = 0; r < 4; r++) QKVB[orow[r] + col] = (short)f2b(c[r]);
  }
}

// ---------------- attention (register-tiled VALU, f32) ----------------
__global__ __launch_bounds__(256) void attn_kernel(
    const short* __restrict__ QKVB, short* __restrict__ ATB) {
  int blk = blockIdx.x;
  int h = blk & 7;
  int sb = blk >> 3;
  size_t tok0 = (size_t)sb * 85;
  __shared__ float q[88 * 16];
  __shared__ float kT[16 * 88];
  __shared__ float vT[16 * 90];
  __shared__ float att[85 * 85];
  const short* base = QKVB + tok0 * 384;
  for (int e = threadIdx.x; e < 88 * 16; e += 256) {
    int n = e >> 4, d = e & 15;
    if (n < 85) {
      q[n * 16 + d] = b2f(base[n * 384 + h * 16 + d]);
      kT[d * 88 + n] = b2f(base[n * 384 + 128 + h * 16 + d]);
      vT[d * 90 + n] = b2f(base[n * 384 + 256 + h * 16 + d]);
    } else {
      q[n * 16 + d] = 0.f;
      kT[d * 88 + n] = 0.f;
      vT[d * 90 + n] = 0.f;
    }
  }
  __syncthreads();
  // scores: 4x4 register tiles, 22x22 tiles cover 88x88
  for (int t = threadIdx.x; t < 22 * 22; t += 256) {
    int n0 = (t / 22) * 4, m0 = (t % 22) * 4;
    float acc[4][4];
#pragma unroll
    for (int i = 0; i < 4; i++)
#pragma unroll
      for (int j = 0; j < 4; j++) acc[i][j] = 0.f;
    for (int d = 0; d < 16; d++) {
      float qd[4], kd[4];
#pragma unroll
      for (int i = 0; i < 4; i++) qd[i] = q[(n0 + i) * 16 + d];
#pragma unroll
      for (int j = 0; j < 4; j++) kd[j] = kT[d * 88 + m0 + j];
#pragma unroll
      for (int i = 0; i < 4; i++)
#pragma unroll
        for (int j = 0; j < 4; j++) acc[i][j] += qd[i] * kd[j];
    }
#pragma unroll
    for (int i = 0; i < 4; i++)
      if (n0 + i < 85)
#pragma unroll
        for (int j = 0; j < 4; j++)
          if (m0 + j < 85) att[(n0 + i) * 85 + m0 + j] = acc[i][j];
  }
  __syncthreads();
  // wave-parallel softmax: one wave per row
  int wid = threadIdx.x >> 6, lane = threadIdx.x & 63;
  for (int r = wid; r < 85; r += 4) {
    float v0 = att[r * 85 + lane];
    float v1 = (lane < 21) ? att[r * 85 + 64 + lane] : -1e30f;
    float mx = fmaxf(v0, v1);
#pragma unroll
    for (int off = 32; off > 0; off >>= 1) mx = fmaxf(mx, __shfl_xor(mx, off));
    float e0 = __expf(v0 - mx);
    float e1 = (lane < 21) ? __expf(v1 - mx) : 0.f;
    float ss = e0 + e1;
#pragma unroll
    for (int off = 32; off > 0; off >>= 1) ss += __shfl_xor(ss, off);
    float inv = 1.f / ss;
    att[r * 85 + lane] = e0 * inv;
    if (lane < 21) att[r * 85 + 64 + lane] = e1 * inv;
  }
  __syncthreads();
  // PV: 4n x 2d register tiles (22*8 = 176 tiles)
  for (int t = threadIdx.x; t < 22 * 8; t += 256) {
    int n0 = (t / 8) * 4, d0 = (t % 8) * 2;
    float acc[4][2];
#pragma unroll
    for (int i = 0; i < 4; i++) { acc[i][0] = 0.f; acc[i][1] = 0.f; }
    for (int m = 0; m < 85; m++) {
      float vv0 = vT[d0 * 90 + m];
      float vv1 = vT[(d0 + 1) * 90 + m];
#pragma unroll
      for (int i = 0; i < 4; i++) {
        float ai = (n0 + i < 85) ? att[(n0 + i) * 85 + m] : 0.f;
        acc[i][0] += ai * vv0;
        acc[i][1] += ai * vv1;
      }
    }
#pragma unroll
    for (int i = 0; i < 4; i++)
      if (n0 + i < 85) {
        size_t o = (tok0 + n0 + i) * 128 + h * 16 + d0;
        ATB[o] = (short)f2b(acc[i][0]);
        ATB[o + 1] = (short)f2b(acc[i][1]);
      }
  }
}

// ---------------- proj (K=128, N=128) + residual into X ----------------
__global__ __launch_bounds__(256) void proj_mfma(
    const short* __restrict__ ATB, const short* __restrict__ Wt,
    float* __restrict__ X) {
  int wid = threadIdx.x >> 6, lane = threadIdx.x & 63;
  int col15 = lane & 15, kg = lane >> 4;
  size_t tok0 = (size_t)blockIdx.x * 64 + wid * 16;
  const short* abase = ATB + (tok0 + col15) * 128 + kg * 8;
  bf16x8 a[4];
#pragma unroll
  for (int ks = 0; ks < 4; ks++) a[ks] = ldg8(abase + ks * 32);
  size_t orow[4];
#pragma unroll
  for (int r = 0; r < 4; r++) orow[r] = (tok0 + kg * 4 + r) * 128;
  for (int nt = 0; nt < 8; nt++) {
    const short* bbase = Wt + (size_t)(nt * 16 + col15) * 128 + kg * 8;
    f32x4 c = (f32x4){0.f, 0.f, 0.f, 0.f};
#pragma unroll
    for (int ks = 0; ks < 4; ks++) c = MFMA(a[ks], ldg8(bbase + ks * 32), c, 0, 0, 0);
    int col = nt * 16 + col15;
#pragma unroll
    for (int r = 0; r < 4; r++) X[orow[r] + col] += c[r];
  }
}

// ---------------- fused MLP, single wave, hidden in swizzled LDS ----------------
__global__ __launch_bounds__(64) void ff_mfma(
    short* __restrict__ XB, const short* __restrict__ W1t, const float* __restrict__ b1,
    const short* __restrict__ W2t, const float* __restrict__ b2, float* __restrict__ X) {
  __shared__ short hid[16 * 512];  // swizzled bf16 [16][512]
  int lane = threadIdx.x;
  int col15 = lane & 15, kg = lane >> 4;
  size_t tok0 = (size_t)blockIdx.x * 16;
  const short* abase = XB + (tok0 + col15) * 128 + kg * 8;
  bf16x8 a[4];
#pragma unroll
  for (int ks = 0; ks < 4; ks++) a[ks] = ldg8(abase + ks * 32);
  char* hb = (char*)hid;
  // stage 1: hid = relu(ln2 @ W1 + b1), bf16
  for (int nt = 0; nt < 32; nt++) {
    const short* bbase = W1t + (size_t)(nt * 16 + col15) * 128 + kg * 8;
    f32x4 c = (f32x4){0.f, 0.f, 0.f, 0.f};
#pragma unroll
    for (int ks = 0; ks < 4; ks++) c = MFMA(a[ks], ldg8(bbase + ks * 32), c, 0, 0, 0);
    int col = nt * 16 + col15;
    float bb = b1[col];
#pragma unroll
    for (int r = 0; r < 4; r++) {
      int row = kg * 4 + r;
      float v = fmaxf(c[r] + bb, 0.f);
      int off = ((row << 10) + (col << 1)) ^ ((row & 7) << 4);
      *(short*)(hb + off) = (short)f2b(v);
    }
  }
  __syncthreads();
  // stage 2: X += hid @ W2 + b2 ; XB = bf16(X)
  bf16x8 hh[16];
#pragma unroll
  for (int ks = 0; ks < 16; ks++) {
    int row = col15;
    int k0 = ks * 32 + kg * 8;
    int off = ((row << 10) + (k0 << 1)) ^ ((row & 7) << 4);
    hh[ks] = *(const bf16x8*)(hb + off);
  }
  size_t orow[4];
#pragma unroll
  for (int r = 0; r < 4; r++) orow[r] = (tok0 + kg * 4 + r) * 128;
  for (int nt = 0; nt < 8; nt++) {
    const short* bbase = W2t + (size_t)(nt * 16 + col15) * 512 + kg * 8;
    f32x4 c = (f32x4){0.f, 0.f, 0.f, 0.f};
#pragma unroll
    for (int ks = 0; ks < 16; ks++) c = MFMA(hh[ks], ldg8(bbase + ks * 32), c, 0, 0, 0);
    int col = nt * 16 + col15;
    float bb = b2[col];
#pragma unroll
    for (int r = 0; r < 4; r++) {
      float v = X[orow[r] + col] + c[r] + bb;
      X[orow[r] + col] = v;
      XB[orow[r] + col] = (short)f2b(v);
    }
  }
}

// ---------------- un-partition + reverse projection (K=128) ----------------
template <int CHout>
__global__ __launch_bounds__(256) void rev_mfma(
    const short* __restrict__ XB, const short* __restrict__ Wt,
    const float* __restrict__ bias, float* __restrict__ out,
    int hsShift, int wsShift, int tokOff) {
  int wid = threadIdx.x >> 6, lane = threadIdx.x & 63;
  int col15 = lane & 15, kg = lane >> 4;
  int p0 = blockIdx.x * 64 + wid * 16;
  int atok = tokmap(p0 + col15, hsShift, wsShift, tokOff);
  const short* abase = XB + (size_t)atok * 128 + kg * 8;
  bf16x8 a[4];
#pragma unroll
  for (int ks = 0; ks < 4; ks++) a[ks] = ldg8(abase + ks * 32);
  size_t orow[4];
#pragma unroll
  for (int r = 0; r < 4; r++) orow[r] = (size_t)(p0 + kg * 4 + r) * CHout;
  for (int nt = 0; nt < CHout / 16; nt++) {
    const short* bbase = Wt + (size_t)(nt * 16 + col15) * 128 + kg * 8;
    f32x4 c = (f32x4){0.f, 0.f, 0.f, 0.f};
#pragma unroll
    for (int ks = 0; ks < 4; ks++) c = MFMA(a[ks], ldg8(bbase + ks * 32), c, 0, 0, 0);
    int col = nt * 16 + col15;
    float bb = bias[col];
#pragma unroll
    for (int r = 0; r < 4; r++) out[orow[r] + col] = c[r] + bb;
  }
}

extern "C" void kernel_launch(void* const* d_in, const int* in_sizes, int n_in,
                              void* d_out, int out_size, void* d_ws, size_t ws_size,
                              hipStream_t stream) {
  const float* x[4]; const float* fcW[4]; const float* fcb[4];
  const float* revW[4]; const float* revb[4];
  for (int j = 0; j < 4; j++) {
    x[j]    = (const float*)d_in[j * 5 + 0];
    fcW[j]  = (const float*)d_in[j * 5 + 1];
    fcb[j]  = (const float*)d_in[j * 5 + 2];
    revW[j] = (const float*)d_in[j * 5 + 3];
    revb[j] = (const float*)d_in[j * 5 + 4];
  }
  const float* ln1g = (const float*)d_in[20];
  const float* ln1b = (const float*)d_in[21];
  const float* ln2g = (const float*)d_in[22];
  const float* ln2b = (const float*)d_in[23];
  const float* qkvW = (const float*)d_in[24];
  const float* projW = (const float*)d_in[25];
  const float* fc1W = (const float*)d_in[26];
  const float* fc1b = (const float*)d_in[27];
  const float* fc2W = (const float*)d_in[28];
  const float* fc2b = (const float*)d_in[29];

  // workspace layout
  float* X    = (float*)d_ws;                           // NTOK*128 f32
  short* QKVB = (short*)(X + (size_t)NTOK * 128);       // NTOK*384 bf16
  short* XB   = QKVB + (size_t)NTOK * 384;              // NTOK*128 bf16
  short* ATB  = XB + (size_t)NTOK * 128;                // NTOK*128 bf16
  short* XIN  = ATB + (size_t)NTOK * 128;               // 15728640 bf16
  short* WT   = XIN + (size_t)15728640;                 // 688128 bf16

  static const int CH[4] = {128, 256, 512, 1024};
  static const int hsS[4] = {6, 5, 4, 3};
  static const int wsS[4] = {3, 2, 1, 0};
  static const int tokOff[4] = {0, 64, 80, 84};
  // XIN segment element offsets
  static const int xinOff[5] = {0, 8388608, 12582912, 14680064, 15728640};
  // WT segment element offsets
  // fcWt: 0,16384,49152,114688 ; revWt: 245760,262144,294912,360448
  // qkvWt 491520, projWt 540672, fc1Wt 557056, fc2Wt 622592
  static const int fcWtOff[4] = {0, 16384, 49152, 114688};
  static const int revWtOff[4] = {245760, 262144, 294912, 360448};
  const int qkvWtOff = 491520, projWtOff = 540672, fc1WtOff = 557056, fc2WtOff = 622592;

  // input conversion
  CvtX cx;
  for (int j = 0; j < 4; j++) { cx.src[j] = x[j]; cx.dst[j] = XIN + xinOff[j]; }
  for (int j = 0; j < 5; j++) cx.off[j] = xinOff[j];
  cvt_x_kernel<<<15360, 256, 0, stream>>>(cx);

  // weight prep
  PrepW pw;
  int cum = 0;
  auto setw = [&](int idx, const float* src, short* dst, int K, int N) {
    pw.src[idx] = src; pw.dst[idx] = dst;
    int ksh = 0; while ((1 << ksh) < K) ksh++;
    pw.kshift[idx] = ksh; pw.N[idx] = N;
    pw.off[idx] = cum; cum += K * N;
  };
  for (int j = 0; j < 4; j++) setw(j, fcW[j], WT + fcWtOff[j], CH[j], 128);
  for (int j = 0; j < 4; j++) setw(4 + j, revW[j], WT + revWtOff[j], 128, CH[j]);
  setw(8, qkvW, WT + qkvWtOff, 128, 384);
  setw(9, projW, WT + projWtOff, 128, 128);
  setw(10, fc1W, WT + fc1WtOff, 128, 512);
  setw(11, fc2W, WT + fc2WtOff, 512, 128);
  pw.off[12] = cum;  // 688128
  prep_w_kernel<<<2688, 256, 0, stream>>>(pw);

  // fc + partition
  fc_mfma<128><<<1024, 256, 0, stream>>>(XIN + xinOff[0], WT + fcWtOff[0], fcb[0], X, hsS[0], wsS[0], tokOff[0]);
  fc_mfma<256><<<256, 256, 0, stream>>>(XIN + xinOff[1], WT + fcWtOff[1], fcb[1], X, hsS[1], wsS[1], tokOff[1]);
  fc_mfma<512><<<64, 256, 0, stream>>>(XIN + xinOff[2], WT + fcWtOff[2], fcb[2], X, hsS[2], wsS[2], tokOff[2]);
  fc_mfma<1024><<<16, 256, 0, stream>>>(XIN + xinOff[3], WT + fcWtOff[3], fcb[3], X, hsS[3], wsS[3], tokOff[3]);

  ln_kernel<<<NTOK / 4, 256, 0, stream>>>(X, ln1g, ln1b, XB);
  qkv_mfma<<<NTOK / 64, 256, 0, stream>>>(XB, WT + qkvWtOff, QKVB);
  attn_kernel<<<1024 * 8, 256, 0, stream>>>(QKVB, ATB);
  proj_mfma<<<NTOK / 64, 256, 0, stream>>>(ATB, WT + projWtOff, X);
  ln_kernel<<<NTOK / 4, 256, 0, stream>>>(X, ln2g, ln2b, XB);
  ff_mfma<<<NTOK / 16, 64, 0, stream>>>(XB, WT + fc1WtOff, fc1b, WT + fc2WtOff, fc2b, X);

  float* out = (float*)d_out;
  size_t outOff = 0;
  {
    int rows = 16 * 64 * 64;
    rev_mfma<128><<<rows / 64, 256, 0, stream>>>(XB, WT + revWtOff[0], revb[0], out + outOff, hsS[0], wsS[0], tokOff[0]);
    outOff += (size_t)rows * 128;
  }
  {
    int rows = 16 * 32 * 32;
    rev_mfma<256><<<rows / 64, 256, 0, stream>>>(XB, WT + revWtOff[1], revb[1], out + outOff, hsS[1], wsS[1], tokOff[1]);
    outOff += (size_t)rows * 256;
  }
  {
    int rows = 16 * 16 * 16;
    rev_mfma<512><<<rows / 64, 256, 0, stream>>>(XB, WT + revWtOff[2], revb[2], out + outOff, hsS[2], wsS[2], tokOff[2]);
    outOff += (size_t)rows * 512;
  }
  {
    int rows = 16 * 8 * 8;
    rev_mfma<1024><<<rows / 64, 256, 0, stream>>>(XB, WT + revWtOff[3], revb[3], out + outOff, hsS[3], wsS[3], tokOff[3]);
    outOff += (size_t)rows * 1024;
  }
}

// Round 3
// 620.243 us; speedup vs baseline: 2.8286x; 1.3718x over previous
//
#include <hip/hip_runtime.h>
#include <hip/hip_bf16.h>

#define NTOK 87040  // 1024 windows * 85 tokens

typedef __attribute__((ext_vector_type(8))) short bf16x8;
typedef __attribute__((ext_vector_type(4))) float f32x4;

#define MFMA __builtin_amdgcn_mfma_f32_16x16x32_bf16

__device__ __forceinline__ unsigned short f2b(float f) {
  unsigned int u; __builtin_memcpy(&u, &f, 4);
  u += 0x7fffu + ((u >> 16) & 1u);  // RNE
  return (unsigned short)(u >> 16);
}
__device__ __forceinline__ float b2f(short s) {
  unsigned int u = ((unsigned int)(unsigned short)s) << 16;
  float f; __builtin_memcpy(&f, &u, 4);
  return f;
}
__device__ __forceinline__ bf16x8 ldg8(const short* p) { return *(const bf16x8*)p; }

// natural spatial row p -> window token index
__device__ __forceinline__ int tokmap(int p, int hsShift, int wsShift, int tokOff) {
  int HSm = (1 << hsShift) - 1;
  int w = p & HSm;
  int h = (p >> hsShift) & HSm;
  int b = p >> (2 * hsShift);
  int bi = h >> wsShift, bj = w >> wsShift;
  int wsm = (1 << wsShift) - 1;
  int tt = ((h & wsm) << wsShift) + (w & wsm);
  return ((((b << 3) | bi) << 3) | bj) * 85 + tokOff + tt;
}

// ---------------- input fp32 -> bf16 ----------------
struct CvtX {
  const float* src[4];
  short* dst[4];
  int off[5];  // element offsets
};
__global__ __launch_bounds__(256) void cvt_x_kernel(CvtX p) {
  int e = (blockIdx.x * 256 + threadIdx.x) * 4;
  int s = 0;
#pragma unroll
  for (int t = 0; t < 4; t++) if (e >= p.off[t + 1]) s = t + 1;
  if (s >= 4) return;
  int local = e - p.off[s];
  float4 v = *(const float4*)(p.src[s] + local);
  unsigned int lo = ((unsigned int)f2b(v.y) << 16) | f2b(v.x);
  unsigned int hi = ((unsigned int)f2b(v.w) << 16) | f2b(v.z);
  uint2 o; o.x = lo; o.y = hi;
  *(uint2*)(p.dst[s] + local) = o;
}

// ---------------- weights: fp32 [K][N] -> bf16 [N][K] ----------------
struct PrepW {
  const float* src[12];
  short* dst[12];
  int kshift[12];
  int N[12];
  int off[13];
};
__global__ __launch_bounds__(256) void prep_w_kernel(PrepW p) {
  int i = blockIdx.x * 256 + threadIdx.x;
  int s = 0;
#pragma unroll
  for (int t = 0; t < 12; t++) if (i >= p.off[t + 1]) s = t + 1;
  if (s >= 12) return;
  int e = i - p.off[s];
  int K = 1 << p.kshift[s];
  int n = e >> p.kshift[s];
  int k = e & (K - 1);
  p.dst[s][e] = (short)f2b(p.src[s][(size_t)k * p.N[s] + n]);
}

// ---------------- fc + window partition (MFMA) ----------------
template <int CH>
__global__ __launch_bounds__(256) void fc_mfma(
    const short* __restrict__ XIN, const short* __restrict__ Wt,
    const float* __restrict__ bias, float* __restrict__ X,
    int hsShift, int wsShift, int tokOff) {
  int wid = threadIdx.x >> 6, lane = threadIdx.x & 63;
  int col15 = lane & 15, kg = lane >> 4;
  int p0 = blockIdx.x * 64 + wid * 16;
  const short* abase = XIN + (size_t)(p0 + col15) * CH + kg * 8;
  f32x4 c[8];
#pragma unroll
  for (int nt = 0; nt < 8; nt++) c[nt] = (f32x4){0.f, 0.f, 0.f, 0.f};
  for (int ks = 0; ks < CH / 32; ks++) {
    bf16x8 a = ldg8(abase + ks * 32);
#pragma unroll
    for (int nt = 0; nt < 8; nt++) {
      bf16x8 b = ldg8(Wt + (size_t)(nt * 16 + col15) * CH + ks * 32 + kg * 8);
      c[nt] = MFMA(a, b, c[nt], 0, 0, 0);
    }
  }
  size_t obase[4];
#pragma unroll
  for (int r = 0; r < 4; r++)
    obase[r] = (size_t)tokmap(p0 + kg * 4 + r, hsShift, wsShift, tokOff) * 128;
#pragma unroll
  for (int nt = 0; nt < 8; nt++) {
    int col = nt * 16 + col15;
    float bb = bias[col];
#pragma unroll
    for (int r = 0; r < 4; r++) X[obase[r] + col] = c[nt][r] + bb;
  }
}

// ---------------- LayerNorm: one wave per token, bf16 out ----------------
__global__ __launch_bounds__(256) void ln_kernel(
    const float* __restrict__ X, const float* __restrict__ g,
    const float* __restrict__ b, short* __restrict__ out) {
  int wid = threadIdx.x >> 6, lane = threadIdx.x & 63;
  size_t tok = (size_t)blockIdx.x * 4 + wid;
  float2 v = *(const float2*)(X + tok * 128 + lane * 2);
  float s = v.x + v.y;
#pragma unroll
  for (int off = 32; off > 0; off >>= 1) s += __shfl_xor(s, off);
  float mean = s * (1.f / 128.f);
  float dx = v.x - mean, dy = v.y - mean;
  float q = dx * dx + dy * dy;
#pragma unroll
  for (int off = 32; off > 0; off >>= 1) q += __shfl_xor(q, off);
  float inv = rsqrtf(q * (1.f / 128.f) + 1e-6f);
  float2 gg = *(const float2*)(g + lane * 2);
  float2 bb = *(const float2*)(b + lane * 2);
  float o0 = dx * inv * gg.x + bb.x;
  float o1 = dy * inv * gg.y + bb.y;
  unsigned int pk = ((unsigned int)f2b(o1) << 16) | f2b(o0);
  *(unsigned int*)(out + tok * 128 + lane * 2) = pk;
}

// ---------------- QKV (K=128, N=384), head-major output ----------------
// QKVH layout: [which(3)][head(8)][NTOK][16]
__global__ __launch_bounds__(256) void qkv_mfma(
    const short* __restrict__ XB, const short* __restrict__ Wt,
    short* __restrict__ QKVH) {
  int wid = threadIdx.x >> 6, lane = threadIdx.x & 63;
  int col15 = lane & 15, kg = lane >> 4;
  size_t tok0 = (size_t)blockIdx.x * 64 + wid * 16;
  const short* abase = XB + (tok0 + col15) * 128 + kg * 8;
  bf16x8 a[4];
#pragma unroll
  for (int ks = 0; ks < 4; ks++) a[ks] = ldg8(abase + ks * 32);
  for (int nt = 0; nt < 24; nt++) {
    const short* bbase = Wt + (size_t)(nt * 16 + col15) * 128 + kg * 8;
    f32x4 c = (f32x4){0.f, 0.f, 0.f, 0.f};
#pragma unroll
    for (int ks = 0; ks < 4; ks++) c = MFMA(a[ks], ldg8(bbase + ks * 32), c, 0, 0, 0);
    size_t hb = (size_t)nt * NTOK;  // nt = which*8 + head
#pragma unroll
    for (int r = 0; r < 4; r++)
      QKVH[(hb + tok0 + kg * 4 + r) * 16 + col15] = (short)f2b(c[r]);
  }
}

// ---------------- MFMA attention: one wave per (window, head) ----------------
#define PLD 104  // LDS row stride (elements): 208B, 16B-aligned, 2-way banks
__global__ __launch_bounds__(64) void attn_mfma(
    const short* __restrict__ QKVH, short* __restrict__ ATB) {
  int blk = blockIdx.x;
  int h = blk & 7, sb = blk >> 3;
  size_t tok0 = (size_t)sb * 85;
  __shared__ short P[96 * PLD];
  __shared__ short vT[16 * PLD];
  int lane = threadIdx.x;
  int col15 = lane & 15, kg = lane >> 4;
  const short* Qp = QKVH + (size_t)h * NTOK * 16;
  const short* Kp = QKVH + (size_t)(8 + h) * NTOK * 16;
  const short* Vp = QKVH + (size_t)(16 + h) * NTOK * 16;

  // stage V^T (d-major), zero cols m in [85,96)
#pragma unroll
  for (int i = 0; i < 3; i++) {
    int idx = i * 64 + lane;
    if (idx < 170) {
      int m = idx >> 1, half = (idx & 1) << 3;
      bf16x8 v = ldg8(Vp + (tok0 + m) * 16 + half);
#pragma unroll
      for (int j = 0; j < 8; j++) vT[(half + j) * PLD + m] = v[j];
    }
  }
  for (int i = lane; i < 176; i += 64) {
    int d = i / 11, m = 85 + (i - (i / 11) * 11);
    vT[d * PLD + m] = 0;
  }

  bf16x8 z8 = {0, 0, 0, 0, 0, 0, 0, 0};
  // K fragments (B operand of QK^T reads K row-major; kg>=2 is K-dim pad)
  bf16x8 kb[6];
#pragma unroll
  for (int nt = 0; nt < 6; nt++) {
    int tk = nt * 16 + col15; if (tk > 84) tk = 84;
    kb[nt] = ldg8(Kp + (tok0 + tk) * 16 + (kg & 1) * 8);
    if (kg >= 2) kb[nt] = z8;
  }

  // QK^T + in-register softmax, in two row-halves (register pressure)
  for (int half = 0; half < 2; half++) {
    bf16x8 qa[3];
#pragma unroll
    for (int m3 = 0; m3 < 3; m3++) {
      int tq = (half * 3 + m3) * 16 + col15; if (tq > 84) tq = 84;
      qa[m3] = ldg8(Qp + (tok0 + tq) * 16 + (kg & 1) * 8);
      if (kg >= 2) qa[m3] = z8;
    }
    f32x4 acc[3][6];
#pragma unroll
    for (int m3 = 0; m3 < 3; m3++)
#pragma unroll
      for (int nt = 0; nt < 6; nt++) acc[m3][nt] = (f32x4){0.f, 0.f, 0.f, 0.f};
#pragma unroll
    for (int nt = 0; nt < 6; nt++)
#pragma unroll
      for (int m3 = 0; m3 < 3; m3++)
        acc[m3][nt] = MFMA(qa[m3], kb[nt], acc[m3][nt], 0, 0, 0);
#pragma unroll
    for (int m3 = 0; m3 < 3; m3++) {
#pragma unroll
      for (int r = 0; r < 4; r++) {
        float v[6];
#pragma unroll
        for (int nt = 0; nt < 6; nt++) v[nt] = acc[m3][nt][r];
        if (col15 >= 5) v[5] = -3e30f;  // mask cols >= 85
        float mx = fmaxf(fmaxf(fmaxf(v[0], v[1]), fmaxf(v[2], v[3])), fmaxf(v[4], v[5]));
#pragma unroll
        for (int s = 1; s < 16; s <<= 1) mx = fmaxf(mx, __shfl_xor(mx, s));
        float sum = 0.f;
#pragma unroll
        for (int nt = 0; nt < 6; nt++) { v[nt] = __expf(v[nt] - mx); sum += v[nt]; }
#pragma unroll
        for (int s = 1; s < 16; s <<= 1) sum += __shfl_xor(sum, s);
        float inv = 1.f / sum;
        int n = (half * 3 + m3) * 16 + kg * 4 + r;
#pragma unroll
        for (int nt = 0; nt < 6; nt++)
          P[n * PLD + nt * 16 + col15] = (short)f2b(v[nt] * inv);
      }
    }
  }
  __syncthreads();

  // PV: O = P @ V   (A-frags from P_lds, B-frags from vT)
  bf16x8 bv[3];
#pragma unroll
  for (int ks = 0; ks < 3; ks++)
    bv[ks] = *(const bf16x8*)&vT[col15 * PLD + ks * 32 + kg * 8];
#pragma unroll
  for (int rt = 0; rt < 6; rt++) {
    f32x4 o = (f32x4){0.f, 0.f, 0.f, 0.f};
#pragma unroll
    for (int ks = 0; ks < 3; ks++) {
      bf16x8 pa = *(const bf16x8*)&P[(rt * 16 + col15) * PLD + ks * 32 + kg * 8];
      o = MFMA(pa, bv[ks], o, 0, 0, 0);
    }
#pragma unroll
    for (int r = 0; r < 4; r++) {
      int n = rt * 16 + kg * 4 + r;
      if (n < 85)
        ATB[(tok0 + n) * 128 + h * 16 + col15] = (short)f2b(o[r]);
    }
  }
}

// ---------------- proj (K=128, N=128) + residual into X ----------------
__global__ __launch_bounds__(256) void proj_mfma(
    const short* __restrict__ ATB, const short* __restrict__ Wt,
    float* __restrict__ X) {
  int wid = threadIdx.x >> 6, lane = threadIdx.x & 63;
  int col15 = lane & 15, kg = lane >> 4;
  size_t tok0 = (size_t)blockIdx.x * 64 + wid * 16;
  const short* abase = ATB + (tok0 + col15) * 128 + kg * 8;
  bf16x8 a[4];
#pragma unroll
  for (int ks = 0; ks < 4; ks++) a[ks] = ldg8(abase + ks * 32);
  size_t orow[4];
#pragma unroll
  for (int r = 0; r < 4; r++) orow[r] = (tok0 + kg * 4 + r) * 128;
  for (int nt = 0; nt < 8; nt++) {
    const short* bbase = Wt + (size_t)(nt * 16 + col15) * 128 + kg * 8;
    f32x4 c = (f32x4){0.f, 0.f, 0.f, 0.f};
#pragma unroll
    for (int ks = 0; ks < 4; ks++) c = MFMA(a[ks], ldg8(bbase + ks * 32), c, 0, 0, 0);
    int col = nt * 16 + col15;
#pragma unroll
    for (int r = 0; r < 4; r++) X[orow[r] + col] += c[r];
  }
}

// ---------------- fused MLP, single wave, hidden in swizzled LDS ----------------
__global__ __launch_bounds__(64) void ff_mfma(
    short* __restrict__ XB, const short* __restrict__ W1t, const float* __restrict__ b1,
    const short* __restrict__ W2t, const float* __restrict__ b2, float* __restrict__ X) {
  __shared__ short hid[16 * 512];  // swizzled bf16 [16][512]
  int lane = threadIdx.x;
  int col15 = lane & 15, kg = lane >> 4;
  size_t tok0 = (size_t)blockIdx.x * 16;
  const short* abase = XB + (tok0 + col15) * 128 + kg * 8;
  bf16x8 a[4];
#pragma unroll
  for (int ks = 0; ks < 4; ks++) a[ks] = ldg8(abase + ks * 32);
  char* hb = (char*)hid;
  for (int nt = 0; nt < 32; nt++) {
    const short* bbase = W1t + (size_t)(nt * 16 + col15) * 128 + kg * 8;
    f32x4 c = (f32x4){0.f, 0.f, 0.f, 0.f};
#pragma unroll
    for (int ks = 0; ks < 4; ks++) c = MFMA(a[ks], ldg8(bbase + ks * 32), c, 0, 0, 0);
    int col = nt * 16 + col15;
    float bb = b1[col];
#pragma unroll
    for (int r = 0; r < 4; r++) {
      int row = kg * 4 + r;
      float v = fmaxf(c[r] + bb, 0.f);
      int off = ((row << 10) + (col << 1)) ^ ((row & 7) << 4);
      *(short*)(hb + off) = (short)f2b(v);
    }
  }
  __syncthreads();
  bf16x8 hh[16];
#pragma unroll
  for (int ks = 0; ks < 16; ks++) {
    int row = col15;
    int k0 = ks * 32 + kg * 8;
    int off = ((row << 10) + (k0 << 1)) ^ ((row & 7) << 4);
    hh[ks] = *(const bf16x8*)(hb + off);
  }
  size_t orow[4];
#pragma unroll
  for (int r = 0; r < 4; r++) orow[r] = (tok0 + kg * 4 + r) * 128;
  for (int nt = 0; nt < 8; nt++) {
    const short* bbase = W2t + (size_t)(nt * 16 + col15) * 512 + kg * 8;
    f32x4 c = (f32x4){0.f, 0.f, 0.f, 0.f};
#pragma unroll
    for (int ks = 0; ks < 16; ks++) c = MFMA(hh[ks], ldg8(bbase + ks * 32), c, 0, 0, 0);
    int col = nt * 16 + col15;
    float bb = b2[col];
#pragma unroll
    for (int r = 0; r < 4; r++) {
      float v = X[orow[r] + col] + c[r] + bb;
      X[orow[r] + col] = v;
      XB[orow[r] + col] = (short)f2b(v);
    }
  }
}

// ---------------- un-partition + reverse projection (K=128) ----------------
template <int CHout>
__global__ __launch_bounds__(256) void rev_mfma(
    const short* __restrict__ XB, const short* __restrict__ Wt,
    const float* __restrict__ bias, float* __restrict__ out,
    int hsShift, int wsShift, int tokOff) {
  int wid = threadIdx.x >> 6, lane = threadIdx.x & 63;
  int col15 = lane & 15, kg = lane >> 4;
  int p0 = blockIdx.x * 64 + wid * 16;
  int atok = tokmap(p0 + col15, hsShift, wsShift, tokOff);
  const short* abase = XB + (size_t)atok * 128 + kg * 8;
  bf16x8 a[4];
#pragma unroll
  for (int ks = 0; ks < 4; ks++) a[ks] = ldg8(abase + ks * 32);
  size_t orow[4];
#pragma unroll
  for (int r = 0; r < 4; r++) orow[r] = (size_t)(p0 + kg * 4 + r) * CHout;
  for (int nt = 0; nt < CHout / 16; nt++) {
    const short* bbase = Wt + (size_t)(nt * 16 + col15) * 128 + kg * 8;
    f32x4 c = (f32x4){0.f, 0.f, 0.f, 0.f};
#pragma unroll
    for (int ks = 0; ks < 4; ks++) c = MFMA(a[ks], ldg8(bbase + ks * 32), c, 0, 0, 0);
    int col = nt * 16 + col15;
    float bb = bias[col];
#pragma unroll
    for (int r = 0; r < 4; r++) out[orow[r] + col] = c[r] + bb;
  }
}

extern "C" void kernel_launch(void* const* d_in, const int* in_sizes, int n_in,
                              void* d_out, int out_size, void* d_ws, size_t ws_size,
                              hipStream_t stream) {
  const float* x[4]; const float* fcW[4]; const float* fcb[4];
  const float* revW[4]; const float* revb[4];
  for (int j = 0; j < 4; j++) {
    x[j]    = (const float*)d_in[j * 5 + 0];
    fcW[j]  = (const float*)d_in[j * 5 + 1];
    fcb[j]  = (const float*)d_in[j * 5 + 2];
    revW[j] = (const float*)d_in[j * 5 + 3];
    revb[j] = (const float*)d_in[j * 5 + 4];
  }
  const float* ln1g = (const float*)d_in[20];
  const float* ln1b = (const float*)d_in[21];
  const float* ln2g = (const float*)d_in[22];
  const float* ln2b = (const float*)d_in[23];
  const float* qkvW = (const float*)d_in[24];
  const float* projW = (const float*)d_in[25];
  const float* fc1W = (const float*)d_in[26];
  const float* fc1b = (const float*)d_in[27];
  const float* fc2W = (const float*)d_in[28];
  const float* fc2b = (const float*)d_in[29];

  // workspace layout
  float* X    = (float*)d_ws;                           // NTOK*128 f32
  short* QKVH = (short*)(X + (size_t)NTOK * 128);       // NTOK*384 bf16 (head-major)
  short* XB   = QKVH + (size_t)NTOK * 384;              // NTOK*128 bf16
  short* ATB  = XB + (size_t)NTOK * 128;                // NTOK*128 bf16
  short* XIN  = ATB + (size_t)NTOK * 128;               // 15728640 bf16
  short* WT   = XIN + (size_t)15728640;                 // 688128 bf16

  static const int CH[4] = {128, 256, 512, 1024};
  static const int hsS[4] = {6, 5, 4, 3};
  static const int wsS[4] = {3, 2, 1, 0};
  static const int tokOff[4] = {0, 64, 80, 84};
  static const int xinOff[5] = {0, 8388608, 12582912, 14680064, 15728640};
  static const int fcWtOff[4] = {0, 16384, 49152, 114688};
  static const int revWtOff[4] = {245760, 262144, 294912, 360448};
  const int qkvWtOff = 491520, projWtOff = 540672, fc1WtOff = 557056, fc2WtOff = 622592;

  CvtX cx;
  for (int j = 0; j < 4; j++) { cx.src[j] = x[j]; cx.dst[j] = XIN + xinOff[j]; }
  for (int j = 0; j < 5; j++) cx.off[j] = xinOff[j];
  cvt_x_kernel<<<15360, 256, 0, stream>>>(cx);

  PrepW pw;
  int cum = 0;
  auto setw = [&](int idx, const float* src, short* dst, int K, int N) {
    pw.src[idx] = src; pw.dst[idx] = dst;
    int ksh = 0; while ((1 << ksh) < K) ksh++;
    pw.kshift[idx] = ksh; pw.N[idx] = N;
    pw.off[idx] = cum; cum += K * N;
  };
  for (int j = 0; j < 4; j++) setw(j, fcW[j], WT + fcWtOff[j], CH[j], 128);
  for (int j = 0; j < 4; j++) setw(4 + j, revW[j], WT + revWtOff[j], 128, CH[j]);
  setw(8, qkvW, WT + qkvWtOff, 128, 384);
  setw(9, projW, WT + projWtOff, 128, 128);
  setw(10, fc1W, WT + fc1WtOff, 128, 512);
  setw(11, fc2W, WT + fc2WtOff, 512, 128);
  pw.off[12] = cum;
  prep_w_kernel<<<2688, 256, 0, stream>>>(pw);

  fc_mfma<128><<<1024, 256, 0, stream>>>(XIN + xinOff[0], WT + fcWtOff[0], fcb[0], X, hsS[0], wsS[0], tokOff[0]);
  fc_mfma<256><<<256, 256, 0, stream>>>(XIN + xinOff[1], WT + fcWtOff[1], fcb[1], X, hsS[1], wsS[1], tokOff[1]);
  fc_mfma<512><<<64, 256, 0, stream>>>(XIN + xinOff[2], WT + fcWtOff[2], fcb[2], X, hsS[2], wsS[2], tokOff[2]);
  fc_mfma<1024><<<16, 256, 0, stream>>>(XIN + xinOff[3], WT + fcWtOff[3], fcb[3], X, hsS[3], wsS[3], tokOff[3]);

  ln_kernel<<<NTOK / 4, 256, 0, stream>>>(X, ln1g, ln1b, XB);
  qkv_mfma<<<NTOK / 64, 256, 0, stream>>>(XB, WT + qkvWtOff, QKVH);
  attn_mfma<<<1024 * 8, 64, 0, stream>>>(QKVH, ATB);
  proj_mfma<<<NTOK / 64, 256, 0, stream>>>(ATB, WT + projWtOff, X);
  ln_kernel<<<NTOK / 4, 256, 0, stream>>>(X, ln2g, ln2b, XB);
  ff_mfma<<<NTOK / 16, 64, 0, stream>>>(XB, WT + fc1WtOff, fc1b, WT + fc2WtOff, fc2b, X);

  float* out = (float*)d_out;
  size_t outOff = 0;
  {
    int rows = 16 * 64 * 64;
    rev_mfma<128><<<rows / 64, 256, 0, stream>>>(XB, WT + revWtOff[0], revb[0], out + outOff, hsS[0], wsS[0], tokOff[0]);
    outOff += (size_t)rows * 128;
  }
  {
    int rows = 16 * 32 * 32;
    rev_mfma<256><<<rows / 64, 256, 0, stream>>>(XB, WT + revWtOff[1], revb[1], out + outOff, hsS[1], wsS[1], tokOff[1]);
    outOff += (size_t)rows * 256;
  }
  {
    int rows = 16 * 16 * 16;
    rev_mfma<512><<<rows / 64, 256, 0, stream>>>(XB, WT + revWtOff[2], revb[2], out + outOff, hsS[2], wsS[2], tokOff[2]);
    outOff += (size_t)rows * 512;
  }
  {
    int rows = 16 * 8 * 8;
    rev_mfma<1024><<<rows / 64, 256, 0, stream>>>(XB, WT + revWtOff[3], revb[3], out + outOff, hsS[3], wsS[3], tokOff[3]);
    outOff += (size_t)rows * 1024;
  }
}

// Round 4
// 615.203 us; speedup vs baseline: 2.8518x; 1.0082x over previous
//
#include <hip/hip_runtime.h>
#include <hip/hip_bf16.h>

#define NTOK 87040  // 1024 windows * 85 tokens

typedef __attribute__((ext_vector_type(8))) short bf16x8;
typedef __attribute__((ext_vector_type(4))) float f32x4;

#define MFMA __builtin_amdgcn_mfma_f32_16x16x32_bf16

__device__ __forceinline__ unsigned short f2b(float f) {
  unsigned int u; __builtin_memcpy(&u, &f, 4);
  u += 0x7fffu + ((u >> 16) & 1u);  // RNE
  return (unsigned short)(u >> 16);
}
__device__ __forceinline__ float b2f(short s) {
  unsigned int u = ((unsigned int)(unsigned short)s) << 16;
  float f; __builtin_memcpy(&f, &u, 4);
  return f;
}
__device__ __forceinline__ bf16x8 ldg8(const short* p) { return *(const bf16x8*)p; }

// natural spatial row p -> window token index
__device__ __forceinline__ int tokmap(int p, int hsShift, int wsShift, int tokOff) {
  int HSm = (1 << hsShift) - 1;
  int w = p & HSm;
  int h = (p >> hsShift) & HSm;
  int b = p >> (2 * hsShift);
  int bi = h >> wsShift, bj = w >> wsShift;
  int wsm = (1 << wsShift) - 1;
  int tt = ((h & wsm) << wsShift) + (w & wsm);
  return ((((b << 3) | bi) << 3) | bj) * 85 + tokOff + tt;
}

// ---------------- input fp32 -> bf16 ----------------
struct CvtX {
  const float* src[4];
  short* dst[4];
  int off[5];  // element offsets
};
__global__ __launch_bounds__(256) void cvt_x_kernel(CvtX p) {
  int e = (blockIdx.x * 256 + threadIdx.x) * 4;
  int s = 0;
#pragma unroll
  for (int t = 0; t < 4; t++) if (e >= p.off[t + 1]) s = t + 1;
  if (s >= 4) return;
  int local = e - p.off[s];
  float4 v = *(const float4*)(p.src[s] + local);
  unsigned int lo = ((unsigned int)f2b(v.y) << 16) | f2b(v.x);
  unsigned int hi = ((unsigned int)f2b(v.w) << 16) | f2b(v.z);
  uint2 o; o.x = lo; o.y = hi;
  *(uint2*)(p.dst[s] + local) = o;
}

// ---------------- weights: fp32 [K][N] -> bf16 [N][K] ----------------
struct PrepW {
  const float* src[12];
  short* dst[12];
  int kshift[12];
  int N[12];
  int off[13];
};
__global__ __launch_bounds__(256) void prep_w_kernel(PrepW p) {
  int i = blockIdx.x * 256 + threadIdx.x;
  int s = 0;
#pragma unroll
  for (int t = 0; t < 12; t++) if (i >= p.off[t + 1]) s = t + 1;
  if (s >= 12) return;
  int e = i - p.off[s];
  int K = 1 << p.kshift[s];
  int n = e >> p.kshift[s];
  int k = e & (K - 1);
  p.dst[s][e] = (short)f2b(p.src[s][(size_t)k * p.N[s] + n]);
}

// ---------------- fc + window partition (MFMA) ----------------
template <int CH>
__global__ __launch_bounds__(256) void fc_mfma(
    const short* __restrict__ XIN, const short* __restrict__ Wt,
    const float* __restrict__ bias, float* __restrict__ X,
    int hsShift, int wsShift, int tokOff) {
  int wid = threadIdx.x >> 6, lane = threadIdx.x & 63;
  int col15 = lane & 15, kg = lane >> 4;
  int p0 = blockIdx.x * 64 + wid * 16;
  const short* abase = XIN + (size_t)(p0 + col15) * CH + kg * 8;
  f32x4 c[8];
#pragma unroll
  for (int nt = 0; nt < 8; nt++) c[nt] = (f32x4){0.f, 0.f, 0.f, 0.f};
  for (int ks = 0; ks < CH / 32; ks++) {
    bf16x8 a = ldg8(abase + ks * 32);
#pragma unroll
    for (int nt = 0; nt < 8; nt++) {
      bf16x8 b = ldg8(Wt + (size_t)(nt * 16 + col15) * CH + ks * 32 + kg * 8);
      c[nt] = MFMA(a, b, c[nt], 0, 0, 0);
    }
  }
  size_t obase[4];
#pragma unroll
  for (int r = 0; r < 4; r++)
    obase[r] = (size_t)tokmap(p0 + kg * 4 + r, hsShift, wsShift, tokOff) * 128;
#pragma unroll
  for (int nt = 0; nt < 8; nt++) {
    int col = nt * 16 + col15;
    float bb = bias[col];
#pragma unroll
    for (int r = 0; r < 4; r++) X[obase[r] + col] = c[nt][r] + bb;
  }
}

// ---------------- LayerNorm: one wave per token, bf16 out ----------------
__global__ __launch_bounds__(256) void ln_kernel(
    const float* __restrict__ X, const float* __restrict__ g,
    const float* __restrict__ b, short* __restrict__ out) {
  int wid = threadIdx.x >> 6, lane = threadIdx.x & 63;
  size_t tok = (size_t)blockIdx.x * 4 + wid;
  float2 v = *(const float2*)(X + tok * 128 + lane * 2);
  float s = v.x + v.y;
#pragma unroll
  for (int off = 32; off > 0; off >>= 1) s += __shfl_xor(s, off);
  float mean = s * (1.f / 128.f);
  float dx = v.x - mean, dy = v.y - mean;
  float q = dx * dx + dy * dy;
#pragma unroll
  for (int off = 32; off > 0; off >>= 1) q += __shfl_xor(q, off);
  float inv = rsqrtf(q * (1.f / 128.f) + 1e-6f);
  float2 gg = *(const float2*)(g + lane * 2);
  float2 bb = *(const float2*)(b + lane * 2);
  float o0 = dx * inv * gg.x + bb.x;
  float o1 = dy * inv * gg.y + bb.y;
  unsigned int pk = ((unsigned int)f2b(o1) << 16) | f2b(o0);
  *(unsigned int*)(out + tok * 128 + lane * 2) = pk;
}

// ---------------- QKV (K=128, N=384), head-major output ----------------
// QKVH layout: [which(3)][head(8)][NTOK][16]
__global__ __launch_bounds__(256) void qkv_mfma(
    const short* __restrict__ XB, const short* __restrict__ Wt,
    short* __restrict__ QKVH) {
  int wid = threadIdx.x >> 6, lane = threadIdx.x & 63;
  int col15 = lane & 15, kg = lane >> 4;
  size_t tok0 = (size_t)blockIdx.x * 64 + wid * 16;
  const short* abase = XB + (tok0 + col15) * 128 + kg * 8;
  bf16x8 a[4];
#pragma unroll
  for (int ks = 0; ks < 4; ks++) a[ks] = ldg8(abase + ks * 32);
  for (int nt = 0; nt < 24; nt++) {
    const short* bbase = Wt + (size_t)(nt * 16 + col15) * 128 + kg * 8;
    f32x4 c = (f32x4){0.f, 0.f, 0.f, 0.f};
#pragma unroll
    for (int ks = 0; ks < 4; ks++) c = MFMA(a[ks], ldg8(bbase + ks * 32), c, 0, 0, 0);
    size_t hb = (size_t)nt * NTOK;  // nt = which*8 + head
#pragma unroll
    for (int r = 0; r < 4; r++)
      QKVH[(hb + tok0 + kg * 4 + r) * 16 + col15] = (short)f2b(c[r]);
  }
}

// ---------------- MFMA attention: one wave per (window, head) ----------------
#define PLD 104  // LDS row stride (elements): 208B, 16B-aligned, 2-way banks
__global__ __launch_bounds__(64) void attn_mfma(
    const short* __restrict__ QKVH, short* __restrict__ ATB) {
  int blk = blockIdx.x;
  int h = blk & 7, sb = blk >> 3;
  size_t tok0 = (size_t)sb * 85;
  __shared__ short P[96 * PLD];
  __shared__ short vT[16 * PLD];
  int lane = threadIdx.x;
  int col15 = lane & 15, kg = lane >> 4;
  const short* Qp = QKVH + (size_t)h * NTOK * 16;
  const short* Kp = QKVH + (size_t)(8 + h) * NTOK * 16;
  const short* Vp = QKVH + (size_t)(16 + h) * NTOK * 16;

  // stage V^T (d-major), zero cols m in [85,96)
#pragma unroll
  for (int i = 0; i < 3; i++) {
    int idx = i * 64 + lane;
    if (idx < 170) {
      int m = idx >> 1, half = (idx & 1) << 3;
      bf16x8 v = ldg8(Vp + (tok0 + m) * 16 + half);
#pragma unroll
      for (int j = 0; j < 8; j++) vT[(half + j) * PLD + m] = v[j];
    }
  }
  for (int i = lane; i < 176; i += 64) {
    int d = i / 11, m = 85 + (i - (i / 11) * 11);
    vT[d * PLD + m] = 0;
  }

  bf16x8 z8 = {0, 0, 0, 0, 0, 0, 0, 0};
  // K fragments (B operand of QK^T reads K row-major; kg>=2 is K-dim pad)
  bf16x8 kb[6];
#pragma unroll
  for (int nt = 0; nt < 6; nt++) {
    int tk = nt * 16 + col15; if (tk > 84) tk = 84;
    kb[nt] = ldg8(Kp + (tok0 + tk) * 16 + (kg & 1) * 8);
    if (kg >= 2) kb[nt] = z8;
  }

  // QK^T + in-register softmax, in two row-halves (register pressure)
  for (int half = 0; half < 2; half++) {
    bf16x8 qa[3];
#pragma unroll
    for (int m3 = 0; m3 < 3; m3++) {
      int tq = (half * 3 + m3) * 16 + col15; if (tq > 84) tq = 84;
      qa[m3] = ldg8(Qp + (tok0 + tq) * 16 + (kg & 1) * 8);
      if (kg >= 2) qa[m3] = z8;
    }
    f32x4 acc[3][6];
#pragma unroll
    for (int m3 = 0; m3 < 3; m3++)
#pragma unroll
      for (int nt = 0; nt < 6; nt++) acc[m3][nt] = (f32x4){0.f, 0.f, 0.f, 0.f};
#pragma unroll
    for (int nt = 0; nt < 6; nt++)
#pragma unroll
      for (int m3 = 0; m3 < 3; m3++)
        acc[m3][nt] = MFMA(qa[m3], kb[nt], acc[m3][nt], 0, 0, 0);
#pragma unroll
    for (int m3 = 0; m3 < 3; m3++) {
#pragma unroll
      for (int r = 0; r < 4; r++) {
        float v[6];
#pragma unroll
        for (int nt = 0; nt < 6; nt++) v[nt] = acc[m3][nt][r];
        if (col15 >= 5) v[5] = -3e30f;  // mask cols >= 85
        float mx = fmaxf(fmaxf(fmaxf(v[0], v[1]), fmaxf(v[2], v[3])), fmaxf(v[4], v[5]));
#pragma unroll
        for (int s = 1; s < 16; s <<= 1) mx = fmaxf(mx, __shfl_xor(mx, s));
        float sum = 0.f;
#pragma unroll
        for (int nt = 0; nt < 6; nt++) { v[nt] = __expf(v[nt] - mx); sum += v[nt]; }
#pragma unroll
        for (int s = 1; s < 16; s <<= 1) sum += __shfl_xor(sum, s);
        float inv = 1.f / sum;
        int n = (half * 3 + m3) * 16 + kg * 4 + r;
#pragma unroll
        for (int nt = 0; nt < 6; nt++)
          P[n * PLD + nt * 16 + col15] = (short)f2b(v[nt] * inv);
      }
    }
  }
  __syncthreads();

  // PV: O = P @ V   (A-frags from P_lds, B-frags from vT)
  bf16x8 bv[3];
#pragma unroll
  for (int ks = 0; ks < 3; ks++)
    bv[ks] = *(const bf16x8*)&vT[col15 * PLD + ks * 32 + kg * 8];
#pragma unroll
  for (int rt = 0; rt < 6; rt++) {
    f32x4 o = (f32x4){0.f, 0.f, 0.f, 0.f};
#pragma unroll
    for (int ks = 0; ks < 3; ks++) {
      bf16x8 pa = *(const bf16x8*)&P[(rt * 16 + col15) * PLD + ks * 32 + kg * 8];
      o = MFMA(pa, bv[ks], o, 0, 0, 0);
    }
#pragma unroll
    for (int r = 0; r < 4; r++) {
      int n = rt * 16 + kg * 4 + r;
      if (n < 85)
        ATB[(tok0 + n) * 128 + h * 16 + col15] = (short)f2b(o[r]);
    }
  }
}

// ---------------- proj (K=128, N=128) + residual into X ----------------
__global__ __launch_bounds__(256) void proj_mfma(
    const short* __restrict__ ATB, const short* __restrict__ Wt,
    float* __restrict__ X) {
  int wid = threadIdx.x >> 6, lane = threadIdx.x & 63;
  int col15 = lane & 15, kg = lane >> 4;
  size_t tok0 = (size_t)blockIdx.x * 64 + wid * 16;
  const short* abase = ATB + (tok0 + col15) * 128 + kg * 8;
  bf16x8 a[4];
#pragma unroll
  for (int ks = 0; ks < 4; ks++) a[ks] = ldg8(abase + ks * 32);
  size_t orow[4];
#pragma unroll
  for (int r = 0; r < 4; r++) orow[r] = (tok0 + kg * 4 + r) * 128;
  for (int nt = 0; nt < 8; nt++) {
    const short* bbase = Wt + (size_t)(nt * 16 + col15) * 128 + kg * 8;
    f32x4 c = (f32x4){0.f, 0.f, 0.f, 0.f};
#pragma unroll
    for (int ks = 0; ks < 4; ks++) c = MFMA(a[ks], ldg8(bbase + ks * 32), c, 0, 0, 0);
    int col = nt * 16 + col15;
#pragma unroll
    for (int r = 0; r < 4; r++) X[orow[r] + col] += c[r];
  }
}

// ---------------- fused MLP: 4 waves, 64 tokens/block, hidden in swizzled LDS ----
__global__ __launch_bounds__(256) void ff_mfma(
    short* __restrict__ XB, const short* __restrict__ W1t, const float* __restrict__ b1,
    const short* __restrict__ W2t, const float* __restrict__ b2,
    const float* __restrict__ X) {
  __shared__ short hid[64 * 512];  // 64KB, swizzled bf16 [64][512]
  int wv = threadIdx.x >> 6, lane = threadIdx.x & 63;
  int col15 = lane & 15, kg = lane >> 4;
  size_t tok0 = (size_t)blockIdx.x * 64 + wv * 16;
  const short* abase = XB + (tok0 + col15) * 128 + kg * 8;
  bf16x8 a[4];
#pragma unroll
  for (int ks = 0; ks < 4; ks++) a[ks] = ldg8(abase + ks * 32);
  char* hb = (char*)hid;
  // stage 1: hid = relu(ln2 @ W1 + b1), bf16
  for (int nt = 0; nt < 32; nt++) {
    const short* bbase = W1t + (size_t)(nt * 16 + col15) * 128 + kg * 8;
    f32x4 c = (f32x4){0.f, 0.f, 0.f, 0.f};
#pragma unroll
    for (int ks = 0; ks < 4; ks++) c = MFMA(a[ks], ldg8(bbase + ks * 32), c, 0, 0, 0);
    int col = nt * 16 + col15;
    float bb = b1[col];
#pragma unroll
    for (int r = 0; r < 4; r++) {
      int row = wv * 16 + kg * 4 + r;
      float v = fmaxf(c[r] + bb, 0.f);
      int off = ((row << 10) + (col << 1)) ^ ((row & 7) << 4);
      *(short*)(hb + off) = (short)f2b(v);
    }
  }
  __syncthreads();
  // stage 2: out = hid @ W2 + b2 + X(residual) -> XB (bf16 only; X is dead after)
  bf16x8 hh[16];
#pragma unroll
  for (int ks = 0; ks < 16; ks++) {
    int row = wv * 16 + col15;
    int k0 = ks * 32 + kg * 8;
    int off = ((row << 10) + (k0 << 1)) ^ ((row & 7) << 4);
    hh[ks] = *(const bf16x8*)(hb + off);
  }
  size_t orow[4];
#pragma unroll
  for (int r = 0; r < 4; r++) orow[r] = (tok0 + kg * 4 + r) * 128;
  for (int nt = 0; nt < 8; nt++) {
    const short* bbase = W2t + (size_t)(nt * 16 + col15) * 512 + kg * 8;
    f32x4 c = (f32x4){0.f, 0.f, 0.f, 0.f};
#pragma unroll
    for (int ks = 0; ks < 16; ks++) c = MFMA(hh[ks], ldg8(bbase + ks * 32), c, 0, 0, 0);
    int col = nt * 16 + col15;
    float bb = b2[col];
#pragma unroll
    for (int r = 0; r < 4; r++) {
      float v = X[orow[r] + col] + c[r] + bb;
      XB[orow[r] + col] = (short)f2b(v);
    }
  }
}

// ---------------- un-partition + reverse projection (K=128) ----------------
template <int CHout>
__global__ __launch_bounds__(256) void rev_mfma(
    const short* __restrict__ XB, const short* __restrict__ Wt,
    const float* __restrict__ bias, float* __restrict__ out,
    int hsShift, int wsShift, int tokOff) {
  int wid = threadIdx.x >> 6, lane = threadIdx.x & 63;
  int col15 = lane & 15, kg = lane >> 4;
  int p0 = blockIdx.x * 64 + wid * 16;
  int atok = tokmap(p0 + col15, hsShift, wsShift, tokOff);
  const short* abase = XB + (size_t)atok * 128 + kg * 8;
  bf16x8 a[4];
#pragma unroll
  for (int ks = 0; ks < 4; ks++) a[ks] = ldg8(abase + ks * 32);
  size_t orow[4];
#pragma unroll
  for (int r = 0; r < 4; r++) orow[r] = (size_t)(p0 + kg * 4 + r) * CHout;
  for (int nt = 0; nt < CHout / 16; nt++) {
    const short* bbase = Wt + (size_t)(nt * 16 + col15) * 128 + kg * 8;
    f32x4 c = (f32x4){0.f, 0.f, 0.f, 0.f};
#pragma unroll
    for (int ks = 0; ks < 4; ks++) c = MFMA(a[ks], ldg8(bbase + ks * 32), c, 0, 0, 0);
    int col = nt * 16 + col15;
    float bb = bias[col];
#pragma unroll
    for (int r = 0; r < 4; r++) out[orow[r] + col] = c[r] + bb;
  }
}

extern "C" void kernel_launch(void* const* d_in, const int* in_sizes, int n_in,
                              void* d_out, int out_size, void* d_ws, size_t ws_size,
                              hipStream_t stream) {
  const float* x[4]; const float* fcW[4]; const float* fcb[4];
  const float* revW[4]; const float* revb[4];
  for (int j = 0; j < 4; j++) {
    x[j]    = (const float*)d_in[j * 5 + 0];
    fcW[j]  = (const float*)d_in[j * 5 + 1];
    fcb[j]  = (const float*)d_in[j * 5 + 2];
    revW[j] = (const float*)d_in[j * 5 + 3];
    revb[j] = (const float*)d_in[j * 5 + 4];
  }
  const float* ln1g = (const float*)d_in[20];
  const float* ln1b = (const float*)d_in[21];
  const float* ln2g = (const float*)d_in[22];
  const float* ln2b = (const float*)d_in[23];
  const float* qkvW = (const float*)d_in[24];
  const float* projW = (const float*)d_in[25];
  const float* fc1W = (const float*)d_in[26];
  const float* fc1b = (const float*)d_in[27];
  const float* fc2W = (const float*)d_in[28];
  const float* fc2b = (const float*)d_in[29];

  // workspace layout
  float* X    = (float*)d_ws;                           // NTOK*128 f32
  short* QKVH = (short*)(X + (size_t)NTOK * 128);       // NTOK*384 bf16 (head-major)
  short* XB   = QKVH + (size_t)NTOK * 384;              // NTOK*128 bf16
  short* ATB  = XB + (size_t)NTOK * 128;                // NTOK*128 bf16
  short* XIN  = ATB + (size_t)NTOK * 128;               // 15728640 bf16
  short* WT   = XIN + (size_t)15728640;                 // 688128 bf16

  static const int CH[4] = {128, 256, 512, 1024};
  static const int hsS[4] = {6, 5, 4, 3};
  static const int wsS[4] = {3, 2, 1, 0};
  static const int tokOff[4] = {0, 64, 80, 84};
  static const int xinOff[5] = {0, 8388608, 12582912, 14680064, 15728640};
  static const int fcWtOff[4] = {0, 16384, 49152, 114688};
  static const int revWtOff[4] = {245760, 262144, 294912, 360448};
  const int qkvWtOff = 491520, projWtOff = 540672, fc1WtOff = 557056, fc2WtOff = 622592;

  CvtX cx;
  for (int j = 0; j < 4; j++) { cx.src[j] = x[j]; cx.dst[j] = XIN + xinOff[j]; }
  for (int j = 0; j < 5; j++) cx.off[j] = xinOff[j];
  cvt_x_kernel<<<15360, 256, 0, stream>>>(cx);

  PrepW pw;
  int cum = 0;
  auto setw = [&](int idx, const float* src, short* dst, int K, int N) {
    pw.src[idx] = src; pw.dst[idx] = dst;
    int ksh = 0; while ((1 << ksh) < K) ksh++;
    pw.kshift[idx] = ksh; pw.N[idx] = N;
    pw.off[idx] = cum; cum += K * N;
  };
  for (int j = 0; j < 4; j++) setw(j, fcW[j], WT + fcWtOff[j], CH[j], 128);
  for (int j = 0; j < 4; j++) setw(4 + j, revW[j], WT + revWtOff[j], 128, CH[j]);
  setw(8, qkvW, WT + qkvWtOff, 128, 384);
  setw(9, projW, WT + projWtOff, 128, 128);
  setw(10, fc1W, WT + fc1WtOff, 128, 512);
  setw(11, fc2W, WT + fc2WtOff, 512, 128);
  pw.off[12] = cum;
  prep_w_kernel<<<2688, 256, 0, stream>>>(pw);

  fc_mfma<128><<<1024, 256, 0, stream>>>(XIN + xinOff[0], WT + fcWtOff[0], fcb[0], X, hsS[0], wsS[0], tokOff[0]);
  fc_mfma<256><<<256, 256, 0, stream>>>(XIN + xinOff[1], WT + fcWtOff[1], fcb[1], X, hsS[1], wsS[1], tokOff[1]);
  fc_mfma<512><<<64, 256, 0, stream>>>(XIN + xinOff[2], WT + fcWtOff[2], fcb[2], X, hsS[2], wsS[2], tokOff[2]);
  fc_mfma<1024><<<16, 256, 0, stream>>>(XIN + xinOff[3], WT + fcWtOff[3], fcb[3], X, hsS[3], wsS[3], tokOff[3]);

  ln_kernel<<<NTOK / 4, 256, 0, stream>>>(X, ln1g, ln1b, XB);
  qkv_mfma<<<NTOK / 64, 256, 0, stream>>>(XB, WT + qkvWtOff, QKVH);
  attn_mfma<<<1024 * 8, 64, 0, stream>>>(QKVH, ATB);
  proj_mfma<<<NTOK / 64, 256, 0, stream>>>(ATB, WT + projWtOff, X);
  ln_kernel<<<NTOK / 4, 256, 0, stream>>>(X, ln2g, ln2b, XB);
  ff_mfma<<<NTOK / 64, 256, 0, stream>>>(XB, WT + fc1WtOff, fc1b, WT + fc2WtOff, fc2b, X);

  float* out = (float*)d_out;
  size_t outOff = 0;
  {
    int rows = 16 * 64 * 64;
    rev_mfma<128><<<rows / 64, 256, 0, stream>>>(XB, WT + revWtOff[0], revb[0], out + outOff, hsS[0], wsS[0], tokOff[0]);
    outOff += (size_t)rows * 128;
  }
  {
    int rows = 16 * 32 * 32;
    rev_mfma<256><<<rows / 64, 256, 0, stream>>>(XB, WT + revWtOff[1], revb[1], out + outOff, hsS[1], wsS[1], tokOff[1]);
    outOff += (size_t)rows * 256;
  }
  {
    int rows = 16 * 16 * 16;
    rev_mfma<512><<<rows / 64, 256, 0, stream>>>(XB, WT + revWtOff[2], revb[2], out + outOff, hsS[2], wsS[2], tokOff[2]);
    outOff += (size_t)rows * 512;
  }
  {
    int rows = 16 * 8 * 8;
    rev_mfma<1024><<<rows / 64, 256, 0, stream>>>(XB, WT + revWtOff[3], revb[3], out + outOff, hsS[3], wsS[3], tokOff[3]);
    outOff += (size_t)rows * 1024;
  }
}

// Round 5
// 520.776 us; speedup vs baseline: 3.3689x; 1.1813x over previous
//
#include <hip/hip_runtime.h>
#include <hip/hip_bf16.h>

#define NTOK 87040  // 1024 windows * 85 tokens

typedef __attribute__((ext_vector_type(8))) short bf16x8;
typedef __attribute__((ext_vector_type(4))) float f32x4;

#define MFMA __builtin_amdgcn_mfma_f32_16x16x32_bf16

__device__ __forceinline__ unsigned short f2b(float f) {
  unsigned int u; __builtin_memcpy(&u, &f, 4);
  u += 0x7fffu + ((u >> 16) & 1u);  // RNE
  return (unsigned short)(u >> 16);
}
__device__ __forceinline__ float b2f(short s) {
  unsigned int u = ((unsigned int)(unsigned short)s) << 16;
  float f; __builtin_memcpy(&f, &u, 4);
  return f;
}
__device__ __forceinline__ bf16x8 ldg8(const short* p) { return *(const bf16x8*)p; }

// natural spatial row p -> window token index
__device__ __forceinline__ int tokmap(int p, int hsShift, int wsShift, int tokOff) {
  int HSm = (1 << hsShift) - 1;
  int w = p & HSm;
  int h = (p >> hsShift) & HSm;
  int b = p >> (2 * hsShift);
  int bi = h >> wsShift, bj = w >> wsShift;
  int wsm = (1 << wsShift) - 1;
  int tt = ((h & wsm) << wsShift) + (w & wsm);
  return ((((b << 3) | bi) << 3) | bj) * 85 + tokOff + tt;
}

// ---------------- input fp32 -> bf16 ----------------
struct CvtX {
  const float* src[4];
  short* dst[4];
  int off[5];  // element offsets
};
__global__ __launch_bounds__(256) void cvt_x_kernel(CvtX p) {
  int e = (blockIdx.x * 256 + threadIdx.x) * 4;
  int s = 0;
#pragma unroll
  for (int t = 0; t < 4; t++) if (e >= p.off[t + 1]) s = t + 1;
  if (s >= 4) return;
  int local = e - p.off[s];
  float4 v = *(const float4*)(p.src[s] + local);
  unsigned int lo = ((unsigned int)f2b(v.y) << 16) | f2b(v.x);
  unsigned int hi = ((unsigned int)f2b(v.w) << 16) | f2b(v.z);
  uint2 o; o.x = lo; o.y = hi;
  *(uint2*)(p.dst[s] + local) = o;
}

// ---------------- weights: fp32 [K][N] -> bf16 [N][K] ----------------
struct PrepW {
  const float* src[12];
  short* dst[12];
  int kshift[12];
  int N[12];
  int off[13];
};
__global__ __launch_bounds__(256) void prep_w_kernel(PrepW p) {
  int i = blockIdx.x * 256 + threadIdx.x;
  int s = 0;
#pragma unroll
  for (int t = 0; t < 12; t++) if (i >= p.off[t + 1]) s = t + 1;
  if (s >= 12) return;
  int e = i - p.off[s];
  int K = 1 << p.kshift[s];
  int n = e >> p.kshift[s];
  int k = e & (K - 1);
  p.dst[s][e] = (short)f2b(p.src[s][(size_t)k * p.N[s] + n]);
}

// ---------------- fc + window partition (MFMA) ----------------
template <int CH>
__global__ __launch_bounds__(256) void fc_mfma(
    const short* __restrict__ XIN, const short* __restrict__ Wt,
    const float* __restrict__ bias, float* __restrict__ X,
    int hsShift, int wsShift, int tokOff) {
  int wid = threadIdx.x >> 6, lane = threadIdx.x & 63;
  int col15 = lane & 15, kg = lane >> 4;
  int p0 = blockIdx.x * 64 + wid * 16;
  const short* abase = XIN + (size_t)(p0 + col15) * CH + kg * 8;
  f32x4 c[8];
#pragma unroll
  for (int nt = 0; nt < 8; nt++) c[nt] = (f32x4){0.f, 0.f, 0.f, 0.f};
  for (int ks = 0; ks < CH / 32; ks++) {
    bf16x8 a = ldg8(abase + ks * 32);
#pragma unroll
    for (int nt = 0; nt < 8; nt++) {
      bf16x8 b = ldg8(Wt + (size_t)(nt * 16 + col15) * CH + ks * 32 + kg * 8);
      c[nt] = MFMA(a, b, c[nt], 0, 0, 0);
    }
  }
  size_t obase[4];
#pragma unroll
  for (int r = 0; r < 4; r++)
    obase[r] = (size_t)tokmap(p0 + kg * 4 + r, hsShift, wsShift, tokOff) * 128;
#pragma unroll
  for (int nt = 0; nt < 8; nt++) {
    int col = nt * 16 + col15;
    float bb = bias[col];
#pragma unroll
    for (int r = 0; r < 4; r++) X[obase[r] + col] = c[nt][r] + bb;
  }
}

// ---------------- LayerNorm: one wave per token, bf16 out ----------------
__global__ __launch_bounds__(256) void ln_kernel(
    const float* __restrict__ X, const float* __restrict__ g,
    const float* __restrict__ b, short* __restrict__ out) {
  int wid = threadIdx.x >> 6, lane = threadIdx.x & 63;
  size_t tok = (size_t)blockIdx.x * 4 + wid;
  float2 v = *(const float2*)(X + tok * 128 + lane * 2);
  float s = v.x + v.y;
#pragma unroll
  for (int off = 32; off > 0; off >>= 1) s += __shfl_xor(s, off);
  float mean = s * (1.f / 128.f);
  float dx = v.x - mean, dy = v.y - mean;
  float q = dx * dx + dy * dy;
#pragma unroll
  for (int off = 32; off > 0; off >>= 1) q += __shfl_xor(q, off);
  float inv = rsqrtf(q * (1.f / 128.f) + 1e-6f);
  float2 gg = *(const float2*)(g + lane * 2);
  float2 bb = *(const float2*)(b + lane * 2);
  float o0 = dx * inv * gg.x + bb.x;
  float o1 = dy * inv * gg.y + bb.y;
  unsigned int pk = ((unsigned int)f2b(o1) << 16) | f2b(o0);
  *(unsigned int*)(out + tok * 128 + lane * 2) = pk;
}

// ---------------- QKV (K=128, N=384): persistent, weights in registers ------
// QKVH layout: [which(3)][head(8)][NTOK][16]; wave owns 6 nt tiles (96 cols)
__global__ __launch_bounds__(256) void qkv_mfma(
    const short* __restrict__ XB, const short* __restrict__ Wt,
    short* __restrict__ QKVH, int ntiles) {
  int wv = threadIdx.x >> 6, lane = threadIdx.x & 63;
  int col15 = lane & 15, kg = lane >> 4;
  bf16x8 w[6][4];
#pragma unroll
  for (int i = 0; i < 6; i++)
#pragma unroll
    for (int ks = 0; ks < 4; ks++)
      w[i][ks] = ldg8(Wt + (size_t)((wv * 6 + i) * 16 + col15) * 128 + ks * 32 + kg * 8);
  for (int t = blockIdx.x; t < ntiles; t += gridDim.x) {
    size_t tok0 = (size_t)t * 32;
    bf16x8 a[2][4];
#pragma unroll
    for (int m = 0; m < 2; m++)
#pragma unroll
      for (int ks = 0; ks < 4; ks++)
        a[m][ks] = ldg8(XB + (tok0 + m * 16 + col15) * 128 + ks * 32 + kg * 8);
    f32x4 acc[6][2];
#pragma unroll
    for (int i = 0; i < 6; i++)
#pragma unroll
      for (int m = 0; m < 2; m++) acc[i][m] = (f32x4){0.f, 0.f, 0.f, 0.f};
#pragma unroll
    for (int i = 0; i < 6; i++)
#pragma unroll
      for (int m = 0; m < 2; m++)
#pragma unroll
        for (int ks = 0; ks < 4; ks++)
          acc[i][m] = MFMA(a[m][ks], w[i][ks], acc[i][m], 0, 0, 0);
#pragma unroll
    for (int i = 0; i < 6; i++) {
      size_t hb = (size_t)(wv * 6 + i) * NTOK;
#pragma unroll
      for (int m = 0; m < 2; m++)
#pragma unroll
        for (int r = 0; r < 4; r++)
          QKVH[(hb + tok0 + m * 16 + kg * 4 + r) * 16 + col15] = (short)f2b(acc[i][m][r]);
    }
  }
}

// ---------------- MFMA attention: one wave per (window, head) ----------------
#define PLD 104  // LDS row stride (elements): 208B, 16B-aligned, 2-way banks
__global__ __launch_bounds__(64) void attn_mfma(
    const short* __restrict__ QKVH, short* __restrict__ ATB) {
  int blk = blockIdx.x;
  int h = blk & 7, sb = blk >> 3;
  size_t tok0 = (size_t)sb * 85;
  __shared__ short P[96 * PLD];
  __shared__ short vT[16 * PLD];
  int lane = threadIdx.x;
  int col15 = lane & 15, kg = lane >> 4;
  const short* Qp = QKVH + (size_t)h * NTOK * 16;
  const short* Kp = QKVH + (size_t)(8 + h) * NTOK * 16;
  const short* Vp = QKVH + (size_t)(16 + h) * NTOK * 16;

  // stage V^T (d-major), zero cols m in [85,96)
#pragma unroll
  for (int i = 0; i < 3; i++) {
    int idx = i * 64 + lane;
    if (idx < 170) {
      int m = idx >> 1, half = (idx & 1) << 3;
      bf16x8 v = ldg8(Vp + (tok0 + m) * 16 + half);
#pragma unroll
      for (int j = 0; j < 8; j++) vT[(half + j) * PLD + m] = v[j];
    }
  }
  for (int i = lane; i < 176; i += 64) {
    int d = i / 11, m = 85 + (i - (i / 11) * 11);
    vT[d * PLD + m] = 0;
  }

  bf16x8 z8 = {0, 0, 0, 0, 0, 0, 0, 0};
  // K fragments (B operand of QK^T reads K row-major; kg>=2 is K-dim pad)
  bf16x8 kb[6];
#pragma unroll
  for (int nt = 0; nt < 6; nt++) {
    int tk = nt * 16 + col15; if (tk > 84) tk = 84;
    kb[nt] = ldg8(Kp + (tok0 + tk) * 16 + (kg & 1) * 8);
    if (kg >= 2) kb[nt] = z8;
  }

  // QK^T + in-register softmax, in two row-halves (register pressure)
  for (int half = 0; half < 2; half++) {
    bf16x8 qa[3];
#pragma unroll
    for (int m3 = 0; m3 < 3; m3++) {
      int tq = (half * 3 + m3) * 16 + col15; if (tq > 84) tq = 84;
      qa[m3] = ldg8(Qp + (tok0 + tq) * 16 + (kg & 1) * 8);
      if (kg >= 2) qa[m3] = z8;
    }
    f32x4 acc[3][6];
#pragma unroll
    for (int m3 = 0; m3 < 3; m3++)
#pragma unroll
      for (int nt = 0; nt < 6; nt++) acc[m3][nt] = (f32x4){0.f, 0.f, 0.f, 0.f};
#pragma unroll
    for (int nt = 0; nt < 6; nt++)
#pragma unroll
      for (int m3 = 0; m3 < 3; m3++)
        acc[m3][nt] = MFMA(qa[m3], kb[nt], acc[m3][nt], 0, 0, 0);
#pragma unroll
    for (int m3 = 0; m3 < 3; m3++) {
#pragma unroll
      for (int r = 0; r < 4; r++) {
        float v[6];
#pragma unroll
        for (int nt = 0; nt < 6; nt++) v[nt] = acc[m3][nt][r];
        if (col15 >= 5) v[5] = -3e30f;  // mask cols >= 85
        float mx = fmaxf(fmaxf(fmaxf(v[0], v[1]), fmaxf(v[2], v[3])), fmaxf(v[4], v[5]));
#pragma unroll
        for (int s = 1; s < 16; s <<= 1) mx = fmaxf(mx, __shfl_xor(mx, s));
        float sum = 0.f;
#pragma unroll
        for (int nt = 0; nt < 6; nt++) { v[nt] = __expf(v[nt] - mx); sum += v[nt]; }
#pragma unroll
        for (int s = 1; s < 16; s <<= 1) sum += __shfl_xor(sum, s);
        float inv = 1.f / sum;
        int n = (half * 3 + m3) * 16 + kg * 4 + r;
#pragma unroll
        for (int nt = 0; nt < 6; nt++)
          P[n * PLD + nt * 16 + col15] = (short)f2b(v[nt] * inv);
      }
    }
  }
  __syncthreads();

  // PV: O = P @ V   (A-frags from P_lds, B-frags from vT)
  bf16x8 bv[3];
#pragma unroll
  for (int ks = 0; ks < 3; ks++)
    bv[ks] = *(const bf16x8*)&vT[col15 * PLD + ks * 32 + kg * 8];
#pragma unroll
  for (int rt = 0; rt < 6; rt++) {
    f32x4 o = (f32x4){0.f, 0.f, 0.f, 0.f};
#pragma unroll
    for (int ks = 0; ks < 3; ks++) {
      bf16x8 pa = *(const bf16x8*)&P[(rt * 16 + col15) * PLD + ks * 32 + kg * 8];
      o = MFMA(pa, bv[ks], o, 0, 0, 0);
    }
#pragma unroll
    for (int r = 0; r < 4; r++) {
      int n = rt * 16 + kg * 4 + r;
      if (n < 85)
        ATB[(tok0 + n) * 128 + h * 16 + col15] = (short)f2b(o[r]);
    }
  }
}

// ---------------- proj (K=128, N=128): persistent, weights in registers -----
__global__ __launch_bounds__(256) void proj_mfma(
    const short* __restrict__ ATB, const short* __restrict__ Wt,
    float* __restrict__ X, int ntiles) {
  int wv = threadIdx.x >> 6, lane = threadIdx.x & 63;
  int col15 = lane & 15, kg = lane >> 4;
  bf16x8 w[2][4];
#pragma unroll
  for (int i = 0; i < 2; i++)
#pragma unroll
    for (int ks = 0; ks < 4; ks++)
      w[i][ks] = ldg8(Wt + (size_t)((wv * 2 + i) * 16 + col15) * 128 + ks * 32 + kg * 8);
  for (int t = blockIdx.x; t < ntiles; t += gridDim.x) {
    size_t tok0 = (size_t)t * 32;
    bf16x8 a[2][4];
#pragma unroll
    for (int m = 0; m < 2; m++)
#pragma unroll
      for (int ks = 0; ks < 4; ks++)
        a[m][ks] = ldg8(ATB + (tok0 + m * 16 + col15) * 128 + ks * 32 + kg * 8);
    f32x4 acc[2][2];
#pragma unroll
    for (int i = 0; i < 2; i++)
#pragma unroll
      for (int m = 0; m < 2; m++) acc[i][m] = (f32x4){0.f, 0.f, 0.f, 0.f};
#pragma unroll
    for (int i = 0; i < 2; i++)
#pragma unroll
      for (int m = 0; m < 2; m++)
#pragma unroll
        for (int ks = 0; ks < 4; ks++)
          acc[i][m] = MFMA(a[m][ks], w[i][ks], acc[i][m], 0, 0, 0);
#pragma unroll
    for (int i = 0; i < 2; i++) {
      int col = (wv * 2 + i) * 16 + col15;
#pragma unroll
      for (int m = 0; m < 2; m++)
#pragma unroll
        for (int r = 0; r < 4; r++)
          X[(tok0 + m * 16 + kg * 4 + r) * 128 + col] += acc[i][m][r];
    }
  }
}

// ---------------- MLP stage 1: H = relu(XB @ W1 + b1), persistent -----------
__global__ __launch_bounds__(256) void ff1_mfma(
    const short* __restrict__ XB, const short* __restrict__ W1t,
    const float* __restrict__ b1, short* __restrict__ H,
    int tokBase, int ntiles) {
  int wv = threadIdx.x >> 6, lane = threadIdx.x & 63;
  int col15 = lane & 15, kg = lane >> 4;
  bf16x8 w[8][4];
  float bias[8];
#pragma unroll
  for (int i = 0; i < 8; i++) {
    int col = wv * 128 + i * 16 + col15;
#pragma unroll
    for (int ks = 0; ks < 4; ks++)
      w[i][ks] = ldg8(W1t + (size_t)col * 128 + ks * 32 + kg * 8);
    bias[i] = b1[col];
  }
  for (int t = blockIdx.x; t < ntiles; t += gridDim.x) {
    size_t gtok = (size_t)tokBase + (size_t)t * 16;
    size_t ltok = (size_t)t * 16;
    bf16x8 a[4];
#pragma unroll
    for (int ks = 0; ks < 4; ks++)
      a[ks] = ldg8(XB + (gtok + col15) * 128 + ks * 32 + kg * 8);
    f32x4 acc[8];
#pragma unroll
    for (int i = 0; i < 8; i++) acc[i] = (f32x4){0.f, 0.f, 0.f, 0.f};
#pragma unroll
    for (int i = 0; i < 8; i++)
#pragma unroll
      for (int ks = 0; ks < 4; ks++)
        acc[i] = MFMA(a[ks], w[i][ks], acc[i], 0, 0, 0);
#pragma unroll
    for (int i = 0; i < 8; i++) {
      int col = wv * 128 + i * 16 + col15;
#pragma unroll
      for (int r = 0; r < 4; r++)
        H[(ltok + kg * 4 + r) * 512 + col] = (short)f2b(fmaxf(acc[i][r] + bias[i], 0.f));
    }
  }
}

// ---------------- MLP stage 2: XB = bf16(H @ W2 + b2 + X), persistent -------
__global__ __launch_bounds__(256) void ff2_mfma(
    const short* __restrict__ H, const short* __restrict__ W2t,
    const float* __restrict__ b2, const float* __restrict__ X,
    short* __restrict__ XBo, int tokBase, int ntiles) {
  int wv = threadIdx.x >> 6, lane = threadIdx.x & 63;
  int col15 = lane & 15, kg = lane >> 4;
  bf16x8 w[2][16];
  float bias[2];
#pragma unroll
  for (int i = 0; i < 2; i++) {
    int col = (wv * 2 + i) * 16 + col15;
#pragma unroll
    for (int ks = 0; ks < 16; ks++)
      w[i][ks] = ldg8(W2t + (size_t)col * 512 + ks * 32 + kg * 8);
    bias[i] = b2[col];
  }
  for (int t = blockIdx.x; t < ntiles; t += gridDim.x) {
    size_t gtok = (size_t)tokBase + (size_t)t * 16;
    size_t ltok = (size_t)t * 16;
    bf16x8 hh[16];
#pragma unroll
    for (int ks = 0; ks < 16; ks++)
      hh[ks] = ldg8(H + (ltok + col15) * 512 + ks * 32 + kg * 8);
    f32x4 acc[2];
#pragma unroll
    for (int i = 0; i < 2; i++) acc[i] = (f32x4){0.f, 0.f, 0.f, 0.f};
#pragma unroll
    for (int i = 0; i < 2; i++)
#pragma unroll
      for (int ks = 0; ks < 16; ks++)
        acc[i] = MFMA(hh[ks], w[i][ks], acc[i], 0, 0, 0);
#pragma unroll
    for (int i = 0; i < 2; i++) {
      int col = (wv * 2 + i) * 16 + col15;
#pragma unroll
      for (int r = 0; r < 4; r++) {
        size_t idx = (gtok + kg * 4 + r) * 128 + col;
        XBo[idx] = (short)f2b(X[idx] + acc[i][r] + bias[i]);
      }
    }
  }
}

// ---------------- un-partition + reverse projection (K=128) ----------------
template <int CHout>
__global__ __launch_bounds__(256) void rev_mfma(
    const short* __restrict__ XB, const short* __restrict__ Wt,
    const float* __restrict__ bias, float* __restrict__ out,
    int hsShift, int wsShift, int tokOff) {
  int wid = threadIdx.x >> 6, lane = threadIdx.x & 63;
  int col15 = lane & 15, kg = lane >> 4;
  int p0 = blockIdx.x * 64 + wid * 16;
  int atok = tokmap(p0 + col15, hsShift, wsShift, tokOff);
  const short* abase = XB + (size_t)atok * 128 + kg * 8;
  bf16x8 a[4];
#pragma unroll
  for (int ks = 0; ks < 4; ks++) a[ks] = ldg8(abase + ks * 32);
  size_t orow[4];
#pragma unroll
  for (int r = 0; r < 4; r++) orow[r] = (size_t)(p0 + kg * 4 + r) * CHout;
  for (int nt = 0; nt < CHout / 16; nt++) {
    const short* bbase = Wt + (size_t)(nt * 16 + col15) * 128 + kg * 8;
    f32x4 c = (f32x4){0.f, 0.f, 0.f, 0.f};
#pragma unroll
    for (int ks = 0; ks < 4; ks++) c = MFMA(a[ks], ldg8(bbase + ks * 32), c, 0, 0, 0);
    int col = nt * 16 + col15;
    float bb = bias[col];
#pragma unroll
    for (int r = 0; r < 4; r++) out[orow[r] + col] = c[r] + bb;
  }
}

extern "C" void kernel_launch(void* const* d_in, const int* in_sizes, int n_in,
                              void* d_out, int out_size, void* d_ws, size_t ws_size,
                              hipStream_t stream) {
  const float* x[4]; const float* fcW[4]; const float* fcb[4];
  const float* revW[4]; const float* revb[4];
  for (int j = 0; j < 4; j++) {
    x[j]    = (const float*)d_in[j * 5 + 0];
    fcW[j]  = (const float*)d_in[j * 5 + 1];
    fcb[j]  = (const float*)d_in[j * 5 + 2];
    revW[j] = (const float*)d_in[j * 5 + 3];
    revb[j] = (const float*)d_in[j * 5 + 4];
  }
  const float* ln1g = (const float*)d_in[20];
  const float* ln1b = (const float*)d_in[21];
  const float* ln2g = (const float*)d_in[22];
  const float* ln2b = (const float*)d_in[23];
  const float* qkvW = (const float*)d_in[24];
  const float* projW = (const float*)d_in[25];
  const float* fc1W = (const float*)d_in[26];
  const float* fc1b = (const float*)d_in[27];
  const float* fc2W = (const float*)d_in[28];
  const float* fc2b = (const float*)d_in[29];

  // workspace layout
  float* X    = (float*)d_ws;                           // NTOK*128 f32
  short* QKVH = (short*)(X + (size_t)NTOK * 128);       // NTOK*384 bf16 (head-major)
  short* XB   = QKVH + (size_t)NTOK * 384;              // NTOK*128 bf16
  short* ATB  = XB + (size_t)NTOK * 128;                // NTOK*128 bf16
  short* XIN  = ATB + (size_t)NTOK * 128;               // 15728640 bf16
  short* WT   = XIN + (size_t)15728640;                 // 688128 bf16
  // MLP hidden slab (43520 tok * 512 = 22.28M shorts) reuses ATB+XIN
  // (26.87M shorts, both dead by the time ff runs)
  short* H    = ATB;

  static const int CH[4] = {128, 256, 512, 1024};
  static const int hsS[4] = {6, 5, 4, 3};
  static const int wsS[4] = {3, 2, 1, 0};
  static const int tokOff[4] = {0, 64, 80, 84};
  static const int xinOff[5] = {0, 8388608, 12582912, 14680064, 15728640};
  static const int fcWtOff[4] = {0, 16384, 49152, 114688};
  static const int revWtOff[4] = {245760, 262144, 294912, 360448};
  const int qkvWtOff = 491520, projWtOff = 540672, fc1WtOff = 557056, fc2WtOff = 622592;

  CvtX cx;
  for (int j = 0; j < 4; j++) { cx.src[j] = x[j]; cx.dst[j] = XIN + xinOff[j]; }
  for (int j = 0; j < 5; j++) cx.off[j] = xinOff[j];
  cvt_x_kernel<<<15360, 256, 0, stream>>>(cx);

  PrepW pw;
  int cum = 0;
  auto setw = [&](int idx, const float* src, short* dst, int K, int N) {
    pw.src[idx] = src; pw.dst[idx] = dst;
    int ksh = 0; while ((1 << ksh) < K) ksh++;
    pw.kshift[idx] = ksh; pw.N[idx] = N;
    pw.off[idx] = cum; cum += K * N;
  };
  for (int j = 0; j < 4; j++) setw(j, fcW[j], WT + fcWtOff[j], CH[j], 128);
  for (int j = 0; j < 4; j++) setw(4 + j, revW[j], WT + revWtOff[j], 128, CH[j]);
  setw(8, qkvW, WT + qkvWtOff, 128, 384);
  setw(9, projW, WT + projWtOff, 128, 128);
  setw(10, fc1W, WT + fc1WtOff, 128, 512);
  setw(11, fc2W, WT + fc2WtOff, 512, 128);
  pw.off[12] = cum;
  prep_w_kernel<<<2688, 256, 0, stream>>>(pw);

  fc_mfma<128><<<1024, 256, 0, stream>>>(XIN + xinOff[0], WT + fcWtOff[0], fcb[0], X, hsS[0], wsS[0], tokOff[0]);
  fc_mfma<256><<<256, 256, 0, stream>>>(XIN + xinOff[1], WT + fcWtOff[1], fcb[1], X, hsS[1], wsS[1], tokOff[1]);
  fc_mfma<512><<<64, 256, 0, stream>>>(XIN + xinOff[2], WT + fcWtOff[2], fcb[2], X, hsS[2], wsS[2], tokOff[2]);
  fc_mfma<1024><<<16, 256, 0, stream>>>(XIN + xinOff[3], WT + fcWtOff[3], fcb[3], X, hsS[3], wsS[3], tokOff[3]);

  ln_kernel<<<NTOK / 4, 256, 0, stream>>>(X, ln1g, ln1b, XB);
  qkv_mfma<<<1024, 256, 0, stream>>>(XB, WT + qkvWtOff, QKVH, NTOK / 32);
  attn_mfma<<<1024 * 8, 64, 0, stream>>>(QKVH, ATB);
  proj_mfma<<<1024, 256, 0, stream>>>(ATB, WT + projWtOff, X, NTOK / 32);
  ln_kernel<<<NTOK / 4, 256, 0, stream>>>(X, ln2g, ln2b, XB);
  // MLP in 2 token slabs of 43520 (H buffer reuses dead ATB+XIN region)
  ff1_mfma<<<1024, 256, 0, stream>>>(XB, WT + fc1WtOff, fc1b, H, 0, 2720);
  ff2_mfma<<<1024, 256, 0, stream>>>(H, WT + fc2WtOff, fc2b, X, XB, 0, 2720);
  ff1_mfma<<<1024, 256, 0, stream>>>(XB, WT + fc1WtOff, fc1b, H, 43520, 2720);
  ff2_mfma<<<1024, 256, 0, stream>>>(H, WT + fc2WtOff, fc2b, X, XB, 43520, 2720);

  float* out = (float*)d_out;
  size_t outOff = 0;
  {
    int rows = 16 * 64 * 64;
    rev_mfma<128><<<rows / 64, 256, 0, stream>>>(XB, WT + revWtOff[0], revb[0], out + outOff, hsS[0], wsS[0], tokOff[0]);
    outOff += (size_t)rows * 128;
  }
  {
    int rows = 16 * 32 * 32;
    rev_mfma<256><<<rows / 64, 256, 0, stream>>>(XB, WT + revWtOff[1], revb[1], out + outOff, hsS[1], wsS[1], tokOff[1]);
    outOff += (size_t)rows * 256;
  }
  {
    int rows = 16 * 16 * 16;
    rev_mfma<512><<<rows / 64, 256, 0, stream>>>(XB, WT + revWtOff[2], revb[2], out + outOff, hsS[2], wsS[2], tokOff[2]);
    outOff += (size_t)rows * 512;
  }
  {
    int rows = 16 * 8 * 8;
    rev_mfma<1024><<<rows / 64, 256, 0, stream>>>(XB, WT + revWtOff[3], revb[3], out + outOff, hsS[3], wsS[3], tokOff[3]);
    outOff += (size_t)rows * 1024;
  }
}

// Round 6
// 479.354 us; speedup vs baseline: 3.6600x; 1.0864x over previous
//
#include <hip/hip_runtime.h>
#include <hip/hip_bf16.h>

#define NTOK 87040  // 1024 windows * 85 tokens

typedef __attribute__((ext_vector_type(8))) short bf16x8;
typedef __attribute__((ext_vector_type(4))) float f32x4;
typedef __attribute__((ext_vector_type(16))) float f32x16;

#define MFMA __builtin_amdgcn_mfma_f32_16x16x32_bf16
#define MFMA32 __builtin_amdgcn_mfma_f32_32x32x16_bf16

__device__ __forceinline__ unsigned short f2b(float f) {
  unsigned int u; __builtin_memcpy(&u, &f, 4);
  u += 0x7fffu + ((u >> 16) & 1u);  // RNE
  return (unsigned short)(u >> 16);
}
__device__ __forceinline__ float b2f(short s) {
  unsigned int u = ((unsigned int)(unsigned short)s) << 16;
  float f; __builtin_memcpy(&f, &u, 4);
  return f;
}
__device__ __forceinline__ bf16x8 ldg8(const short* p) { return *(const bf16x8*)p; }
__device__ __forceinline__ f32x16 zero16() {
  f32x16 z;
#pragma unroll
  for (int i = 0; i < 16; i++) z[i] = 0.f;
  return z;
}
__device__ __forceinline__ unsigned int pk2(float lo, float hi) {
  float2 t2; t2.x = lo; t2.y = hi;
  __hip_bfloat162 t = __float22bfloat162_rn(t2);
  unsigned int r; __builtin_memcpy(&r, &t, 4);
  return r;
}

// natural spatial row p -> window token index
__device__ __forceinline__ int tokmap(int p, int hsShift, int wsShift, int tokOff) {
  int HSm = (1 << hsShift) - 1;
  int w = p & HSm;
  int h = (p >> hsShift) & HSm;
  int b = p >> (2 * hsShift);
  int bi = h >> wsShift, bj = w >> wsShift;
  int wsm = (1 << wsShift) - 1;
  int tt = ((h & wsm) << wsShift) + (w & wsm);
  return ((((b << 3) | bi) << 3) | bj) * 85 + tokOff + tt;
}

// ---------------- input fp32 -> bf16 ----------------
struct CvtX {
  const float* src[4];
  short* dst[4];
  int off[5];  // element offsets
};
__global__ __launch_bounds__(256) void cvt_x_kernel(CvtX p) {
  int e = (blockIdx.x * 256 + threadIdx.x) * 4;
  int s = 0;
#pragma unroll
  for (int t = 0; t < 4; t++) if (e >= p.off[t + 1]) s = t + 1;
  if (s >= 4) return;
  int local = e - p.off[s];
  float4 v = *(const float4*)(p.src[s] + local);
  unsigned int lo = ((unsigned int)f2b(v.y) << 16) | f2b(v.x);
  unsigned int hi = ((unsigned int)f2b(v.w) << 16) | f2b(v.z);
  uint2 o; o.x = lo; o.y = hi;
  *(uint2*)(p.dst[s] + local) = o;
}

// ---------------- weights: fp32 [K][N] -> bf16 [N][K] ----------------
struct PrepW {
  const float* src[12];
  short* dst[12];
  int kshift[12];
  int N[12];
  int off[13];
};
__global__ __launch_bounds__(256) void prep_w_kernel(PrepW p) {
  int i = blockIdx.x * 256 + threadIdx.x;
  int s = 0;
#pragma unroll
  for (int t = 0; t < 12; t++) if (i >= p.off[t + 1]) s = t + 1;
  if (s >= 12) return;
  int e = i - p.off[s];
  int K = 1 << p.kshift[s];
  int n = e >> p.kshift[s];
  int k = e & (K - 1);
  p.dst[s][e] = (short)f2b(p.src[s][(size_t)k * p.N[s] + n]);
}

// ---------------- fc + window partition + fused LN1 ----------------
// writes X (f32 residual, pre-LN) and XB (bf16, LN'd)
template <int CH>
__global__ __launch_bounds__(256) void fc_mfma(
    const short* __restrict__ XIN, const short* __restrict__ Wt,
    const float* __restrict__ bias, const float* __restrict__ lng,
    const float* __restrict__ lnb, float* __restrict__ X, short* __restrict__ XB,
    int hsShift, int wsShift, int tokOff) {
  int wid = threadIdx.x >> 6, lane = threadIdx.x & 63;
  int col15 = lane & 15, kg = lane >> 4;
  int p0 = blockIdx.x * 64 + wid * 16;
  const short* abase = XIN + (size_t)(p0 + col15) * CH + kg * 8;
  f32x4 c[8];
#pragma unroll
  for (int nt = 0; nt < 8; nt++) c[nt] = (f32x4){0.f, 0.f, 0.f, 0.f};
  for (int ks = 0; ks < CH / 32; ks++) {
    bf16x8 a = ldg8(abase + ks * 32);
#pragma unroll
    for (int nt = 0; nt < 8; nt++) {
      bf16x8 b = ldg8(Wt + (size_t)(nt * 16 + col15) * CH + ks * 32 + kg * 8);
      c[nt] = MFMA(a, b, c[nt], 0, 0, 0);
    }
  }
  float vals[8][4], gv[8], bv[8];
#pragma unroll
  for (int nt = 0; nt < 8; nt++) {
    int col = nt * 16 + col15;
    float bb = bias[col];
    gv[nt] = lng[col]; bv[nt] = lnb[col];
#pragma unroll
    for (int r = 0; r < 4; r++) vals[nt][r] = c[nt][r] + bb;
  }
  size_t obase[4];
#pragma unroll
  for (int r = 0; r < 4; r++)
    obase[r] = (size_t)tokmap(p0 + kg * 4 + r, hsShift, wsShift, tokOff) * 128;
#pragma unroll
  for (int r = 0; r < 4; r++) {
    float s1 = 0.f, s2 = 0.f;
#pragma unroll
    for (int nt = 0; nt < 8; nt++) { float v = vals[nt][r]; s1 += v; s2 += v * v; }
#pragma unroll
    for (int m = 1; m < 16; m <<= 1) { s1 += __shfl_xor(s1, m); s2 += __shfl_xor(s2, m); }
    float mean = s1 * (1.f / 128.f);
    float inv = rsqrtf(s2 * (1.f / 128.f) - mean * mean + 1e-6f);
#pragma unroll
    for (int nt = 0; nt < 8; nt++) {
      int col = nt * 16 + col15;
      float v = vals[nt][r];
      X[obase[r] + col] = v;
      XB[obase[r] + col] = (short)f2b((v - mean) * inv * gv[nt] + bv[nt]);
    }
  }
}

// ---------------- QKV (K=128, N=384): persistent, weights in registers ------
// QKVH layout: [which(3)][head(8)][NTOK][16]; wave owns 6 nt tiles (96 cols)
__global__ __launch_bounds__(256) void qkv_mfma(
    const short* __restrict__ XB, const short* __restrict__ Wt,
    short* __restrict__ QKVH, int ntiles) {
  int wv = threadIdx.x >> 6, lane = threadIdx.x & 63;
  int col15 = lane & 15, kg = lane >> 4;
  bf16x8 w[6][4];
#pragma unroll
  for (int i = 0; i < 6; i++)
#pragma unroll
    for (int ks = 0; ks < 4; ks++)
      w[i][ks] = ldg8(Wt + (size_t)((wv * 6 + i) * 16 + col15) * 128 + ks * 32 + kg * 8);
  for (int t = blockIdx.x; t < ntiles; t += gridDim.x) {
    size_t tok0 = (size_t)t * 32;
    bf16x8 a[2][4];
#pragma unroll
    for (int m = 0; m < 2; m++)
#pragma unroll
      for (int ks = 0; ks < 4; ks++)
        a[m][ks] = ldg8(XB + (tok0 + m * 16 + col15) * 128 + ks * 32 + kg * 8);
    f32x4 acc[6][2];
#pragma unroll
    for (int i = 0; i < 6; i++)
#pragma unroll
      for (int m = 0; m < 2; m++) acc[i][m] = (f32x4){0.f, 0.f, 0.f, 0.f};
#pragma unroll
    for (int i = 0; i < 6; i++)
#pragma unroll
      for (int m = 0; m < 2; m++)
#pragma unroll
        for (int ks = 0; ks < 4; ks++)
          acc[i][m] = MFMA(a[m][ks], w[i][ks], acc[i][m], 0, 0, 0);
#pragma unroll
    for (int i = 0; i < 6; i++) {
      size_t hb = (size_t)(wv * 6 + i) * NTOK;
#pragma unroll
      for (int m = 0; m < 2; m++)
#pragma unroll
        for (int r = 0; r < 4; r++)
          QKVH[(hb + tok0 + m * 16 + kg * 4 + r) * 16 + col15] = (short)f2b(acc[i][m][r]);
    }
  }
}

// ---------------- MFMA attention, 32x32x16 swapped-operand form --------------
// S^T = mfma(K, Q): lane holds full q-row slices -> in-register softmax;
// P redistributed to PV B-frags via packed shfl_xor(32); no P LDS.
#define PLD 104
__global__ __launch_bounds__(64) void attn_mfma(
    const short* __restrict__ QKVH, short* __restrict__ ATB) {
  int blk = blockIdx.x;
  int h = blk & 7, sb = blk >> 3;
  size_t tok0 = (size_t)sb * 85;
  __shared__ short vT[16 * PLD];  // V^T [d][tok], zero-padded to 96
  __shared__ short oT[32 * 24];   // O^T bounce [q][d], row stride 24 elems
  int lane = threadIdx.x;
  int c31 = lane & 31, hh = lane >> 5;
  const short* Qp = QKVH + (size_t)h * NTOK * 16;
  const short* Kp = QKVH + (size_t)(8 + h) * NTOK * 16;
  const short* Vp = QKVH + (size_t)(16 + h) * NTOK * 16;

  // stage V^T (d-major), zero cols m in [85,96)
#pragma unroll
  for (int i = 0; i < 3; i++) {
    int idx = i * 64 + lane;
    if (idx < 170) {
      int m = idx >> 1, half = (idx & 1) << 3;
      bf16x8 v = ldg8(Vp + (tok0 + m) * 16 + half);
#pragma unroll
      for (int j = 0; j < 8; j++) vT[(half + j) * PLD + m] = v[j];
    }
  }
  for (int i = lane; i < 176; i += 64) {
    int d = i / 11, m = 85 + i % 11;
    vT[d * PLD + m] = 0;
  }

  // K fragments: A[row=k_tok][k=d]; lane row=c31, d = hh*8..+8
  bf16x8 ka[3];
#pragma unroll
  for (int kt = 0; kt < 3; kt++) {
    int tk = kt * 32 + c31; if (tk > 84) tk = 84;
    ka[kt] = ldg8(Kp + (tok0 + tk) * 16 + hh * 8);
  }
  // V^T fragments: A[row=d][k=tok]; rows 16-31 garbage (unused C rows)
  bf16x8 va[6];
  int dm = lane & 15;
#pragma unroll
  for (int ks = 0; ks < 6; ks++)
    va[ks] = *(const bf16x8*)&vT[dm * PLD + ks * 16 + hh * 8];

#pragma unroll
  for (int qt = 0; qt < 3; qt++) {
    int tq = qt * 32 + c31; if (tq > 84) tq = 84;
    bf16x8 qb = ldg8(Qp + (tok0 + tq) * 16 + hh * 8);
    f32x16 s[3];
#pragma unroll
    for (int kt = 0; kt < 3; kt++) s[kt] = zero16();
#pragma unroll
    for (int kt = 0; kt < 3; kt++) s[kt] = MFMA32(ka[kt], qb, s[kt], 0, 0, 0);
    // mask invalid k rows (only kt=2 can exceed 84)
#pragma unroll
    for (int r = 0; r < 16; r++) {
      int krow = 64 + (r & 3) + 8 * (r >> 2) + 4 * hh;
      if (krow > 84) s[2][r] = -3e30f;
    }
    float mx = -3e30f;
#pragma unroll
    for (int kt = 0; kt < 3; kt++)
#pragma unroll
      for (int r = 0; r < 16; r++) mx = fmaxf(mx, s[kt][r]);
    mx = fmaxf(mx, __shfl_xor(mx, 32));
    float sum = 0.f;
#pragma unroll
    for (int kt = 0; kt < 3; kt++)
#pragma unroll
      for (int r = 0; r < 16; r++) { float e = __expf(s[kt][r] - mx); s[kt][r] = e; sum += e; }
    sum += __shfl_xor(sum, 32);
    float inv = 1.f / sum;
    // pack P into PV B-frags: B[k=tok][col=q]; k = hh*8+j per ks (K=16)
    bf16x8 pb[6];
#pragma unroll
    for (int ks = 0; ks < 6; ks++) {
      int kt = ks >> 1;
      int b = 8 * (ks & 1);
      unsigned int u0 = pk2(s[kt][b + 0] * inv, s[kt][b + 1] * inv);
      unsigned int u1 = pk2(s[kt][b + 2] * inv, s[kt][b + 3] * inv);
      unsigned int v0 = pk2(s[kt][b + 4] * inv, s[kt][b + 5] * inv);
      unsigned int v1 = pk2(s[kt][b + 6] * inv, s[kt][b + 7] * inv);
      unsigned int u0x = (unsigned int)__shfl_xor((int)u0, 32);
      unsigned int u1x = (unsigned int)__shfl_xor((int)u1, 32);
      unsigned int v0x = (unsigned int)__shfl_xor((int)v0, 32);
      unsigned int v1x = (unsigned int)__shfl_xor((int)v1, 32);
      unsigned int wv[4];
      wv[0] = hh ? v0x : u0;   // j 0-1
      wv[1] = hh ? v1x : u1;   // j 2-3
      wv[2] = hh ? v0 : u0x;   // j 4-5
      wv[3] = hh ? v1 : u1x;   // j 6-7
      __builtin_memcpy(&pb[ks], wv, 16);
    }
    // PV: C[row=d][col=q] += V^T * P^T
    f32x16 o = zero16();
#pragma unroll
    for (int ks = 0; ks < 6; ks++) o = MFMA32(va[ks], pb[ks], o, 0, 0, 0);
    // bounce O^T through LDS for coalesced 16B stores
#pragma unroll
    for (int r = 0; r < 8; r++) {
      int d = (r & 3) + 8 * (r >> 2) + 4 * hh;
      oT[c31 * 24 + d] = (short)f2b(o[r]);
    }
    int tl = lane >> 1, hf = (lane & 1) * 8;
    int tq2 = qt * 32 + tl;
    if (tq2 < 85) {
      bf16x8 ov = *(const bf16x8*)&oT[tl * 24 + hf];
      *(bf16x8*)&ATB[(tok0 + tq2) * 128 + h * 16 + hf] = ov;
    }
  }
}

// ---------------- proj (K=128, N=128) + residual + fused LN2 -----------------
// each wave: 16 tokens x full 128 cols; writes X (f32 residual) + XB (LN bf16)
__global__ __launch_bounds__(256) void proj_mfma(
    const short* __restrict__ ATB, const short* __restrict__ Wt,
    const float* __restrict__ lng, const float* __restrict__ lnb,
    float* __restrict__ X, short* __restrict__ XB) {
  int wid = threadIdx.x >> 6, lane = threadIdx.x & 63;
  int col15 = lane & 15, kg = lane >> 4;
  size_t tok0 = (size_t)blockIdx.x * 64 + wid * 16;
  const short* abase = ATB + (tok0 + col15) * 128 + kg * 8;
  bf16x8 a[4];
#pragma unroll
  for (int ks = 0; ks < 4; ks++) a[ks] = ldg8(abase + ks * 32);
  float vals[8][4], gv[8], bv[8];
#pragma unroll
  for (int nt = 0; nt < 8; nt++) {
    const short* bbase = Wt + (size_t)(nt * 16 + col15) * 128 + kg * 8;
    f32x4 acc = (f32x4){0.f, 0.f, 0.f, 0.f};
#pragma unroll
    for (int ks = 0; ks < 4; ks++) acc = MFMA(a[ks], ldg8(bbase + ks * 32), acc, 0, 0, 0);
    int col = nt * 16 + col15;
    gv[nt] = lng[col]; bv[nt] = lnb[col];
#pragma unroll
    for (int r = 0; r < 4; r++)
      vals[nt][r] = acc[r] + X[(tok0 + kg * 4 + r) * 128 + col];
  }
#pragma unroll
  for (int r = 0; r < 4; r++) {
    float s1 = 0.f, s2 = 0.f;
#pragma unroll
    for (int nt = 0; nt < 8; nt++) { float v = vals[nt][r]; s1 += v; s2 += v * v; }
#pragma unroll
    for (int m = 1; m < 16; m <<= 1) { s1 += __shfl_xor(s1, m); s2 += __shfl_xor(s2, m); }
    float mean = s1 * (1.f / 128.f);
    float inv = rsqrtf(s2 * (1.f / 128.f) - mean * mean + 1e-6f);
    size_t row = (tok0 + kg * 4 + r) * 128;
#pragma unroll
    for (int nt = 0; nt < 8; nt++) {
      int col = nt * 16 + col15;
      float v = vals[nt][r];
      X[row + col] = v;
      XB[row + col] = (short)f2b((v - mean) * inv * gv[nt] + bv[nt]);
    }
  }
}

// ---------------- MLP stage 1: H = relu(XB @ W1 + b1), persistent -----------
__global__ __launch_bounds__(256) void ff1_mfma(
    const short* __restrict__ XB, const short* __restrict__ W1t,
    const float* __restrict__ b1, short* __restrict__ H,
    int tokBase, int ntiles) {
  int wv = threadIdx.x >> 6, lane = threadIdx.x & 63;
  int col15 = lane & 15, kg = lane >> 4;
  bf16x8 w[8][4];
  float bias[8];
#pragma unroll
  for (int i = 0; i < 8; i++) {
    int col = wv * 128 + i * 16 + col15;
#pragma unroll
    for (int ks = 0; ks < 4; ks++)
      w[i][ks] = ldg8(W1t + (size_t)col * 128 + ks * 32 + kg * 8);
    bias[i] = b1[col];
  }
  for (int t = blockIdx.x; t < ntiles; t += gridDim.x) {
    size_t gtok = (size_t)tokBase + (size_t)t * 16;
    size_t ltok = (size_t)t * 16;
    bf16x8 a[4];
#pragma unroll
    for (int ks = 0; ks < 4; ks++)
      a[ks] = ldg8(XB + (gtok + col15) * 128 + ks * 32 + kg * 8);
    f32x4 acc[8];
#pragma unroll
    for (int i = 0; i < 8; i++) acc[i] = (f32x4){0.f, 0.f, 0.f, 0.f};
#pragma unroll
    for (int i = 0; i < 8; i++)
#pragma unroll
      for (int ks = 0; ks < 4; ks++)
        acc[i] = MFMA(a[ks], w[i][ks], acc[i], 0, 0, 0);
#pragma unroll
    for (int i = 0; i < 8; i++) {
      int col = wv * 128 + i * 16 + col15;
#pragma unroll
      for (int r = 0; r < 4; r++)
        H[(ltok + kg * 4 + r) * 512 + col] = (short)f2b(fmaxf(acc[i][r] + bias[i], 0.f));
    }
  }
}

// ---------------- MLP stage 2: XB = bf16(H @ W2 + b2 + X), persistent -------
__global__ __launch_bounds__(256) void ff2_mfma(
    const short* __restrict__ H, const short* __restrict__ W2t,
    const float* __restrict__ b2, const float* __restrict__ X,
    short* __restrict__ XBo, int tokBase, int ntiles) {
  int wv = threadIdx.x >> 6, lane = threadIdx.x & 63;
  int col15 = lane & 15, kg = lane >> 4;
  bf16x8 w[2][16];
  float bias[2];
#pragma unroll
  for (int i = 0; i < 2; i++) {
    int col = (wv * 2 + i) * 16 + col15;
#pragma unroll
    for (int ks = 0; ks < 16; ks++)
      w[i][ks] = ldg8(W2t + (size_t)col * 512 + ks * 32 + kg * 8);
    bias[i] = b2[col];
  }
  for (int t = blockIdx.x; t < ntiles; t += gridDim.x) {
    size_t gtok = (size_t)tokBase + (size_t)t * 16;
    size_t ltok = (size_t)t * 16;
    bf16x8 hh[16];
#pragma unroll
    for (int ks = 0; ks < 16; ks++)
      hh[ks] = ldg8(H + (ltok + col15) * 512 + ks * 32 + kg * 8);
    f32x4 acc[2];
#pragma unroll
    for (int i = 0; i < 2; i++) acc[i] = (f32x4){0.f, 0.f, 0.f, 0.f};
#pragma unroll
    for (int i = 0; i < 2; i++)
#pragma unroll
      for (int ks = 0; ks < 16; ks++)
        acc[i] = MFMA(hh[ks], w[i][ks], acc[i], 0, 0, 0);
#pragma unroll
    for (int i = 0; i < 2; i++) {
      int col = (wv * 2 + i) * 16 + col15;
#pragma unroll
      for (int r = 0; r < 4; r++) {
        size_t idx = (gtok + kg * 4 + r) * 128 + col;
        XBo[idx] = (short)f2b(X[idx] + acc[i][r] + bias[i]);
      }
    }
  }
}

// ---------------- un-partition + reverse projection (K=128) ----------------
template <int CHout>
__global__ __launch_bounds__(256) void rev_mfma(
    const short* __restrict__ XB, const short* __restrict__ Wt,
    const float* __restrict__ bias, float* __restrict__ out,
    int hsShift, int wsShift, int tokOff) {
  int wid = threadIdx.x >> 6, lane = threadIdx.x & 63;
  int col15 = lane & 15, kg = lane >> 4;
  int p0 = blockIdx.x * 64 + wid * 16;
  int atok = tokmap(p0 + col15, hsShift, wsShift, tokOff);
  const short* abase = XB + (size_t)atok * 128 + kg * 8;
  bf16x8 a[4];
#pragma unroll
  for (int ks = 0; ks < 4; ks++) a[ks] = ldg8(abase + ks * 32);
  size_t orow[4];
#pragma unroll
  for (int r = 0; r < 4; r++) orow[r] = (size_t)(p0 + kg * 4 + r) * CHout;
  for (int nt = 0; nt < CHout / 16; nt++) {
    const short* bbase = Wt + (size_t)(nt * 16 + col15) * 128 + kg * 8;
    f32x4 c = (f32x4){0.f, 0.f, 0.f, 0.f};
#pragma unroll
    for (int ks = 0; ks < 4; ks++) c = MFMA(a[ks], ldg8(bbase + ks * 32), c, 0, 0, 0);
    int col = nt * 16 + col15;
    float bb = bias[col];
#pragma unroll
    for (int r = 0; r < 4; r++) out[orow[r] + col] = c[r] + bb;
  }
}

extern "C" void kernel_launch(void* const* d_in, const int* in_sizes, int n_in,
                              void* d_out, int out_size, void* d_ws, size_t ws_size,
                              hipStream_t stream) {
  const float* x[4]; const float* fcW[4]; const float* fcb[4];
  const float* revW[4]; const float* revb[4];
  for (int j = 0; j < 4; j++) {
    x[j]    = (const float*)d_in[j * 5 + 0];
    fcW[j]  = (const float*)d_in[j * 5 + 1];
    fcb[j]  = (const float*)d_in[j * 5 + 2];
    revW[j] = (const float*)d_in[j * 5 + 3];
    revb[j] = (const float*)d_in[j * 5 + 4];
  }
  const float* ln1g = (const float*)d_in[20];
  const float* ln1b = (const float*)d_in[21];
  const float* ln2g = (const float*)d_in[22];
  const float* ln2b = (const float*)d_in[23];
  const float* qkvW = (const float*)d_in[24];
  const float* projW = (const float*)d_in[25];
  const float* fc1W = (const float*)d_in[26];
  const float* fc1b = (const float*)d_in[27];
  const float* fc2W = (const float*)d_in[28];
  const float* fc2b = (const float*)d_in[29];

  // workspace layout
  float* X    = (float*)d_ws;                           // NTOK*128 f32
  short* QKVH = (short*)(X + (size_t)NTOK * 128);       // NTOK*384 bf16 (head-major)
  short* XB   = QKVH + (size_t)NTOK * 384;              // NTOK*128 bf16
  short* ATB  = XB + (size_t)NTOK * 128;                // NTOK*128 bf16
  short* XIN  = ATB + (size_t)NTOK * 128;               // 15728640 bf16
  short* WT   = XIN + (size_t)15728640;                 // 688128 bf16
  short* H    = ATB;  // MLP hidden slab reuses dead ATB+XIN region

  static const int CH[4] = {128, 256, 512, 1024};
  static const int hsS[4] = {6, 5, 4, 3};
  static const int wsS[4] = {3, 2, 1, 0};
  static const int tokOff[4] = {0, 64, 80, 84};
  static const int xinOff[5] = {0, 8388608, 12582912, 14680064, 15728640};
  static const int fcWtOff[4] = {0, 16384, 49152, 114688};
  static const int revWtOff[4] = {245760, 262144, 294912, 360448};
  const int qkvWtOff = 491520, projWtOff = 540672, fc1WtOff = 557056, fc2WtOff = 622592;

  CvtX cx;
  for (int j = 0; j < 4; j++) { cx.src[j] = x[j]; cx.dst[j] = XIN + xinOff[j]; }
  for (int j = 0; j < 5; j++) cx.off[j] = xinOff[j];
  cvt_x_kernel<<<15360, 256, 0, stream>>>(cx);

  PrepW pw;
  int cum = 0;
  auto setw = [&](int idx, const float* src, short* dst, int K, int N) {
    pw.src[idx] = src; pw.dst[idx] = dst;
    int ksh = 0; while ((1 << ksh) < K) ksh++;
    pw.kshift[idx] = ksh; pw.N[idx] = N;
    pw.off[idx] = cum; cum += K * N;
  };
  for (int j = 0; j < 4; j++) setw(j, fcW[j], WT + fcWtOff[j], CH[j], 128);
  for (int j = 0; j < 4; j++) setw(4 + j, revW[j], WT + revWtOff[j], 128, CH[j]);
  setw(8, qkvW, WT + qkvWtOff, 128, 384);
  setw(9, projW, WT + projWtOff, 128, 128);
  setw(10, fc1W, WT + fc1WtOff, 128, 512);
  setw(11, fc2W, WT + fc2WtOff, 512, 128);
  pw.off[12] = cum;
  prep_w_kernel<<<2688, 256, 0, stream>>>(pw);

  fc_mfma<128><<<1024, 256, 0, stream>>>(XIN + xinOff[0], WT + fcWtOff[0], fcb[0], ln1g, ln1b, X, XB, hsS[0], wsS[0], tokOff[0]);
  fc_mfma<256><<<256, 256, 0, stream>>>(XIN + xinOff[1], WT + fcWtOff[1], fcb[1], ln1g, ln1b, X, XB, hsS[1], wsS[1], tokOff[1]);
  fc_mfma<512><<<64, 256, 0, stream>>>(XIN + xinOff[2], WT + fcWtOff[2], fcb[2], ln1g, ln1b, X, XB, hsS[2], wsS[2], tokOff[2]);
  fc_mfma<1024><<<16, 256, 0, stream>>>(XIN + xinOff[3], WT + fcWtOff[3], fcb[3], ln1g, ln1b, X, XB, hsS[3], wsS[3], tokOff[3]);

  qkv_mfma<<<1024, 256, 0, stream>>>(XB, WT + qkvWtOff, QKVH, NTOK / 32);
  attn_mfma<<<1024 * 8, 64, 0, stream>>>(QKVH, ATB);
  proj_mfma<<<NTOK / 64, 256, 0, stream>>>(ATB, WT + projWtOff, ln2g, ln2b, X, XB);
  // MLP in 2 token slabs of 43520 (H buffer reuses dead ATB+XIN region)
  ff1_mfma<<<1024, 256, 0, stream>>>(XB, WT + fc1WtOff, fc1b, H, 0, 2720);
  ff2_mfma<<<1024, 256, 0, stream>>>(H, WT + fc2WtOff, fc2b, X, XB, 0, 2720);
  ff1_mfma<<<1024, 256, 0, stream>>>(XB, WT + fc1WtOff, fc1b, H, 43520, 2720);
  ff2_mfma<<<1024, 256, 0, stream>>>(H, WT + fc2WtOff, fc2b, X, XB, 43520, 2720);

  float* out = (float*)d_out;
  size_t outOff = 0;
  {
    int rows = 16 * 64 * 64;
    rev_mfma<128><<<rows / 64, 256, 0, stream>>>(XB, WT + revWtOff[0], revb[0], out + outOff, hsS[0], wsS[0], tokOff[0]);
    outOff += (size_t)rows * 128;
  }
  {
    int rows = 16 * 32 * 32;
    rev_mfma<256><<<rows / 64, 256, 0, stream>>>(XB, WT + revWtOff[1], revb[1], out + outOff, hsS[1], wsS[1], tokOff[1]);
    outOff += (size_t)rows * 256;
  }
  {
    int rows = 16 * 16 * 16;
    rev_mfma<512><<<rows / 64, 256, 0, stream>>>(XB, WT + revWtOff[2], revb[2], out + outOff, hsS[2], wsS[2], tokOff[2]);
    outOff += (size_t)rows * 512;
  }
  {
    int rows = 16 * 8 * 8;
    rev_mfma<1024><<<rows / 64, 256, 0, stream>>>(XB, WT + revWtOff[3], revb[3], out + outOff, hsS[3], wsS[3], tokOff[3]);
    outOff += (size_t)rows * 1024;
  }
}

// Round 7
// 365.133 us; speedup vs baseline: 4.8049x; 1.3128x over previous
//
#include <hip/hip_runtime.h>
#include <hip/hip_bf16.h>

#define NTOK 87040  // 1024 windows * 85 tokens

typedef __attribute__((ext_vector_type(8))) short bf16x8;
typedef __attribute__((ext_vector_type(4))) float f32x4;
typedef __attribute__((ext_vector_type(16))) float f32x16;

#define MFMA __builtin_amdgcn_mfma_f32_16x16x32_bf16
#define MFMA32 __builtin_amdgcn_mfma_f32_32x32x16_bf16

__device__ __forceinline__ unsigned short f2b(float f) {
  unsigned int u; __builtin_memcpy(&u, &f, 4);
  u += 0x7fffu + ((u >> 16) & 1u);  // RNE
  return (unsigned short)(u >> 16);
}
__device__ __forceinline__ float b2f(short s) {
  unsigned int u = ((unsigned int)(unsigned short)s) << 16;
  float f; __builtin_memcpy(&f, &u, 4);
  return f;
}
__device__ __forceinline__ bf16x8 ldg8(const short* p) { return *(const bf16x8*)p; }
__device__ __forceinline__ f32x16 zero16() {
  f32x16 z;
#pragma unroll
  for (int i = 0; i < 16; i++) z[i] = 0.f;
  return z;
}
__device__ __forceinline__ unsigned int pk2(float lo, float hi) {
  float2 t2; t2.x = lo; t2.y = hi;
  __hip_bfloat162 t = __float22bfloat162_rn(t2);
  unsigned int r; __builtin_memcpy(&r, &t, 4);
  return r;
}

// natural spatial row p -> window token index
__device__ __forceinline__ int tokmap(int p, int hsShift, int wsShift, int tokOff) {
  int HSm = (1 << hsShift) - 1;
  int w = p & HSm;
  int h = (p >> hsShift) & HSm;
  int b = p >> (2 * hsShift);
  int bi = h >> wsShift, bj = w >> wsShift;
  int wsm = (1 << wsShift) - 1;
  int tt = ((h & wsm) << wsShift) + (w & wsm);
  return ((((b << 3) | bi) << 3) | bj) * 85 + tokOff + tt;
}

// ---------------- input fp32 -> bf16 ----------------
struct CvtX {
  const float* src[4];
  short* dst[4];
  int off[5];  // element offsets
};
__global__ __launch_bounds__(256) void cvt_x_kernel(CvtX p) {
  int e = (blockIdx.x * 256 + threadIdx.x) * 4;
  int s = 0;
#pragma unroll
  for (int t = 0; t < 4; t++) if (e >= p.off[t + 1]) s = t + 1;
  if (s >= 4) return;
  int local = e - p.off[s];
  float4 v = *(const float4*)(p.src[s] + local);
  unsigned int lo = ((unsigned int)f2b(v.y) << 16) | f2b(v.x);
  unsigned int hi = ((unsigned int)f2b(v.w) << 16) | f2b(v.z);
  uint2 o; o.x = lo; o.y = hi;
  *(uint2*)(p.dst[s] + local) = o;
}

// ---------------- weights: fp32 [K][N] -> bf16 [N][K] ----------------
struct PrepW {
  const float* src[12];
  short* dst[12];
  int kshift[12];
  int N[12];
  int off[13];
};
__global__ __launch_bounds__(256) void prep_w_kernel(PrepW p) {
  int i = blockIdx.x * 256 + threadIdx.x;
  int s = 0;
#pragma unroll
  for (int t = 0; t < 12; t++) if (i >= p.off[t + 1]) s = t + 1;
  if (s >= 12) return;
  int e = i - p.off[s];
  int K = 1 << p.kshift[s];
  int n = e >> p.kshift[s];
  int k = e & (K - 1);
  p.dst[s][e] = (short)f2b(p.src[s][(size_t)k * p.N[s] + n]);
}

// ---------------- fused fc (all 4 levels) + partition + LN1 ----------------
// blocks [0,64): lvl3 split-K; [64,320): lvl2 split-K; [320,576): lvl1;
// [576,1600): lvl0. Split-K: 16-token block, wave w owns K-chunk w,
// partials reduced via LDS (row stride 129 words to dodge bank conflicts).
struct FcAllArgs {
  const short* xin[4];
  const short* wt[4];
  const float* bias[4];
  int hsS[4]; int wsS[4]; int tokOff[4]; int chShift[4];
};
__global__ __launch_bounds__(256) void fc_all(
    FcAllArgs A, const float* __restrict__ lng, const float* __restrict__ lnb,
    float* __restrict__ X, short* __restrict__ XB) {
  __shared__ float red[4][16 * 129];
  int bid = blockIdx.x;
  int lvl, lb;
  if (bid < 64) { lvl = 3; lb = bid; }
  else if (bid < 320) { lvl = 2; lb = bid - 64; }
  else if (bid < 576) { lvl = 1; lb = bid - 320; }
  else { lvl = 0; lb = bid - 576; }
  int wv = threadIdx.x >> 6, lane = threadIdx.x & 63;
  int col15 = lane & 15, kg = lane >> 4;
  const short* XIN = A.xin[lvl];
  const short* Wt = A.wt[lvl];
  const float* bias = A.bias[lvl];
  int CH = 1 << A.chShift[lvl];
  int hsShift = A.hsS[lvl], wsShift = A.wsS[lvl], tokOff = A.tokOff[lvl];

  if (lvl >= 2) {
    // ---- 16-token block, 4-way split-K ----
    int p0 = lb * 16;
    int kb = wv * (CH >> 2);
    const short* abase = XIN + (size_t)(p0 + col15) * CH + kb + kg * 8;
    f32x4 c[8];
#pragma unroll
    for (int nt = 0; nt < 8; nt++) c[nt] = (f32x4){0.f, 0.f, 0.f, 0.f};
    int kiters = CH >> 7;  // (CH/4)/32
    for (int ks = 0; ks < kiters; ks++) {
      bf16x8 a = ldg8(abase + ks * 32);
#pragma unroll
      for (int nt = 0; nt < 8; nt++) {
        bf16x8 b = ldg8(Wt + (size_t)(nt * 16 + col15) * CH + kb + ks * 32 + kg * 8);
        c[nt] = MFMA(a, b, c[nt], 0, 0, 0);
      }
    }
#pragma unroll
    for (int nt = 0; nt < 8; nt++)
#pragma unroll
      for (int r = 0; r < 4; r++)
        red[wv][(kg * 4 + r) * 129 + nt * 16 + col15] = c[nt][r];
    __syncthreads();
    // finish: wave wv handles tokens wv*4..wv*4+3 (kg selects token)
    int tt = wv * 4 + kg;
    float v[8], gv[8], bv[8];
#pragma unroll
    for (int nt = 0; nt < 8; nt++) {
      int col = nt * 16 + col15;
      v[nt] = red[0][tt * 129 + col] + red[1][tt * 129 + col] +
              red[2][tt * 129 + col] + red[3][tt * 129 + col] + bias[col];
      gv[nt] = lng[col]; bv[nt] = lnb[col];
    }
    float s1 = 0.f, s2 = 0.f;
#pragma unroll
    for (int nt = 0; nt < 8; nt++) { s1 += v[nt]; s2 += v[nt] * v[nt]; }
#pragma unroll
    for (int m = 1; m < 16; m <<= 1) { s1 += __shfl_xor(s1, m); s2 += __shfl_xor(s2, m); }
    float mean = s1 * (1.f / 128.f);
    float inv = rsqrtf(s2 * (1.f / 128.f) - mean * mean + 1e-6f);
    size_t row = (size_t)tokmap(p0 + tt, hsShift, wsShift, tokOff) * 128;
#pragma unroll
    for (int nt = 0; nt < 8; nt++) {
      int col = nt * 16 + col15;
      X[row + col] = v[nt];
      XB[row + col] = (short)f2b((v[nt] - mean) * inv * gv[nt] + bv[nt]);
    }
  } else {
    // ---- 64-token block, full K per wave (lvl 0/1) ----
    int p0 = lb * 64 + wv * 16;
    const short* abase = XIN + (size_t)(p0 + col15) * CH + kg * 8;
    f32x4 c[8];
#pragma unroll
    for (int nt = 0; nt < 8; nt++) c[nt] = (f32x4){0.f, 0.f, 0.f, 0.f};
    int kiters = CH >> 5;
    for (int ks = 0; ks < kiters; ks++) {
      bf16x8 a = ldg8(abase + ks * 32);
#pragma unroll
      for (int nt = 0; nt < 8; nt++) {
        bf16x8 b = ldg8(Wt + (size_t)(nt * 16 + col15) * CH + ks * 32 + kg * 8);
        c[nt] = MFMA(a, b, c[nt], 0, 0, 0);
      }
    }
    float vals[8][4], gv[8], bv[8];
#pragma unroll
    for (int nt = 0; nt < 8; nt++) {
      int col = nt * 16 + col15;
      float bb = bias[col];
      gv[nt] = lng[col]; bv[nt] = lnb[col];
#pragma unroll
      for (int r = 0; r < 4; r++) vals[nt][r] = c[nt][r] + bb;
    }
    size_t obase[4];
#pragma unroll
    for (int r = 0; r < 4; r++)
      obase[r] = (size_t)tokmap(p0 + kg * 4 + r, hsShift, wsShift, tokOff) * 128;
#pragma unroll
    for (int r = 0; r < 4; r++) {
      float s1 = 0.f, s2 = 0.f;
#pragma unroll
      for (int nt = 0; nt < 8; nt++) { float v = vals[nt][r]; s1 += v; s2 += v * v; }
#pragma unroll
      for (int m = 1; m < 16; m <<= 1) { s1 += __shfl_xor(s1, m); s2 += __shfl_xor(s2, m); }
      float mean = s1 * (1.f / 128.f);
      float inv = rsqrtf(s2 * (1.f / 128.f) - mean * mean + 1e-6f);
#pragma unroll
      for (int nt = 0; nt < 8; nt++) {
        int col = nt * 16 + col15;
        float v = vals[nt][r];
        X[obase[r] + col] = v;
        XB[obase[r] + col] = (short)f2b((v - mean) * inv * gv[nt] + bv[nt]);
      }
    }
  }
}

// ---------------- QKV (K=128, N=384): persistent, weights in registers ------
// QKVH layout: [which(3)][head(8)][NTOK][16]; wave owns 6 nt tiles (96 cols)
__global__ __launch_bounds__(256) void qkv_mfma(
    const short* __restrict__ XB, const short* __restrict__ Wt,
    short* __restrict__ QKVH, int ntiles) {
  int wv = threadIdx.x >> 6, lane = threadIdx.x & 63;
  int col15 = lane & 15, kg = lane >> 4;
  bf16x8 w[6][4];
#pragma unroll
  for (int i = 0; i < 6; i++)
#pragma unroll
    for (int ks = 0; ks < 4; ks++)
      w[i][ks] = ldg8(Wt + (size_t)((wv * 6 + i) * 16 + col15) * 128 + ks * 32 + kg * 8);
  for (int t = blockIdx.x; t < ntiles; t += gridDim.x) {
    size_t tok0 = (size_t)t * 32;
    bf16x8 a[2][4];
#pragma unroll
    for (int m = 0; m < 2; m++)
#pragma unroll
      for (int ks = 0; ks < 4; ks++)
        a[m][ks] = ldg8(XB + (tok0 + m * 16 + col15) * 128 + ks * 32 + kg * 8);
    f32x4 acc[6][2];
#pragma unroll
    for (int i = 0; i < 6; i++)
#pragma unroll
      for (int m = 0; m < 2; m++) acc[i][m] = (f32x4){0.f, 0.f, 0.f, 0.f};
#pragma unroll
    for (int i = 0; i < 6; i++)
#pragma unroll
      for (int m = 0; m < 2; m++)
#pragma unroll
        for (int ks = 0; ks < 4; ks++)
          acc[i][m] = MFMA(a[m][ks], w[i][ks], acc[i][m], 0, 0, 0);
#pragma unroll
    for (int i = 0; i < 6; i++) {
      size_t hb = (size_t)(wv * 6 + i) * NTOK;
#pragma unroll
      for (int m = 0; m < 2; m++)
#pragma unroll
        for (int r = 0; r < 4; r++)
          QKVH[(hb + tok0 + m * 16 + kg * 4 + r) * 16 + col15] = (short)f2b(acc[i][m][r]);
    }
  }
}

// ---------------- MFMA attention, 32x32x16 swapped-operand form --------------
#define PLD 104
__global__ __launch_bounds__(64) void attn_mfma(
    const short* __restrict__ QKVH, short* __restrict__ ATB) {
  int blk = blockIdx.x;
  int h = blk & 7, sb = blk >> 3;
  size_t tok0 = (size_t)sb * 85;
  __shared__ short vT[16 * PLD];  // V^T [d][tok], zero-padded to 96
  __shared__ short oT[32 * 24];   // O^T bounce [q][d], row stride 24 elems
  int lane = threadIdx.x;
  int c31 = lane & 31, hh = lane >> 5;
  const short* Qp = QKVH + (size_t)h * NTOK * 16;
  const short* Kp = QKVH + (size_t)(8 + h) * NTOK * 16;
  const short* Vp = QKVH + (size_t)(16 + h) * NTOK * 16;

#pragma unroll
  for (int i = 0; i < 3; i++) {
    int idx = i * 64 + lane;
    if (idx < 170) {
      int m = idx >> 1, half = (idx & 1) << 3;
      bf16x8 v = ldg8(Vp + (tok0 + m) * 16 + half);
#pragma unroll
      for (int j = 0; j < 8; j++) vT[(half + j) * PLD + m] = v[j];
    }
  }
  for (int i = lane; i < 176; i += 64) {
    int d = i / 11, m = 85 + i % 11;
    vT[d * PLD + m] = 0;
  }

  bf16x8 ka[3];
#pragma unroll
  for (int kt = 0; kt < 3; kt++) {
    int tk = kt * 32 + c31; if (tk > 84) tk = 84;
    ka[kt] = ldg8(Kp + (tok0 + tk) * 16 + hh * 8);
  }
  bf16x8 va[6];
  int dm = lane & 15;
#pragma unroll
  for (int ks = 0; ks < 6; ks++)
    va[ks] = *(const bf16x8*)&vT[dm * PLD + ks * 16 + hh * 8];

#pragma unroll
  for (int qt = 0; qt < 3; qt++) {
    int tq = qt * 32 + c31; if (tq > 84) tq = 84;
    bf16x8 qb = ldg8(Qp + (tok0 + tq) * 16 + hh * 8);
    f32x16 s[3];
#pragma unroll
    for (int kt = 0; kt < 3; kt++) s[kt] = zero16();
#pragma unroll
    for (int kt = 0; kt < 3; kt++) s[kt] = MFMA32(ka[kt], qb, s[kt], 0, 0, 0);
#pragma unroll
    for (int r = 0; r < 16; r++) {
      int krow = 64 + (r & 3) + 8 * (r >> 2) + 4 * hh;
      if (krow > 84) s[2][r] = -3e30f;
    }
    float mx = -3e30f;
#pragma unroll
    for (int kt = 0; kt < 3; kt++)
#pragma unroll
      for (int r = 0; r < 16; r++) mx = fmaxf(mx, s[kt][r]);
    mx = fmaxf(mx, __shfl_xor(mx, 32));
    float sum = 0.f;
#pragma unroll
    for (int kt = 0; kt < 3; kt++)
#pragma unroll
      for (int r = 0; r < 16; r++) { float e = __expf(s[kt][r] - mx); s[kt][r] = e; sum += e; }
    sum += __shfl_xor(sum, 32);
    float inv = 1.f / sum;
    bf16x8 pb[6];
#pragma unroll
    for (int ks = 0; ks < 6; ks++) {
      int kt = ks >> 1;
      int b = 8 * (ks & 1);
      unsigned int u0 = pk2(s[kt][b + 0] * inv, s[kt][b + 1] * inv);
      unsigned int u1 = pk2(s[kt][b + 2] * inv, s[kt][b + 3] * inv);
      unsigned int v0 = pk2(s[kt][b + 4] * inv, s[kt][b + 5] * inv);
      unsigned int v1 = pk2(s[kt][b + 6] * inv, s[kt][b + 7] * inv);
      unsigned int u0x = (unsigned int)__shfl_xor((int)u0, 32);
      unsigned int u1x = (unsigned int)__shfl_xor((int)u1, 32);
      unsigned int v0x = (unsigned int)__shfl_xor((int)v0, 32);
      unsigned int v1x = (unsigned int)__shfl_xor((int)v1, 32);
      unsigned int wv[4];
      wv[0] = hh ? v0x : u0;
      wv[1] = hh ? v1x : u1;
      wv[2] = hh ? v0 : u0x;
      wv[3] = hh ? v1 : u1x;
      __builtin_memcpy(&pb[ks], wv, 16);
    }
    f32x16 o = zero16();
#pragma unroll
    for (int ks = 0; ks < 6; ks++) o = MFMA32(va[ks], pb[ks], o, 0, 0, 0);
#pragma unroll
    for (int r = 0; r < 8; r++) {
      int d = (r & 3) + 8 * (r >> 2) + 4 * hh;
      oT[c31 * 24 + d] = (short)f2b(o[r]);
    }
    int tl = lane >> 1, hf = (lane & 1) * 8;
    int tq2 = qt * 32 + tl;
    if (tq2 < 85) {
      bf16x8 ov = *(const bf16x8*)&oT[tl * 24 + hf];
      *(bf16x8*)&ATB[(tok0 + tq2) * 128 + h * 16 + hf] = ov;
    }
  }
}

// ---------------- proj (K=128, N=128) + residual + fused LN2 -----------------
__global__ __launch_bounds__(256) void proj_mfma(
    const short* __restrict__ ATB, const short* __restrict__ Wt,
    const float* __restrict__ lng, const float* __restrict__ lnb,
    float* __restrict__ X, short* __restrict__ XB) {
  int wid = threadIdx.x >> 6, lane = threadIdx.x & 63;
  int col15 = lane & 15, kg = lane >> 4;
  size_t tok0 = (size_t)blockIdx.x * 64 + wid * 16;
  const short* abase = ATB + (tok0 + col15) * 128 + kg * 8;
  bf16x8 a[4];
#pragma unroll
  for (int ks = 0; ks < 4; ks++) a[ks] = ldg8(abase + ks * 32);
  float vals[8][4], gv[8], bv[8];
#pragma unroll
  for (int nt = 0; nt < 8; nt++) {
    const short* bbase = Wt + (size_t)(nt * 16 + col15) * 128 + kg * 8;
    f32x4 acc = (f32x4){0.f, 0.f, 0.f, 0.f};
#pragma unroll
    for (int ks = 0; ks < 4; ks++) acc = MFMA(a[ks], ldg8(bbase + ks * 32), acc, 0, 0, 0);
    int col = nt * 16 + col15;
    gv[nt] = lng[col]; bv[nt] = lnb[col];
#pragma unroll
    for (int r = 0; r < 4; r++)
      vals[nt][r] = acc[r] + X[(tok0 + kg * 4 + r) * 128 + col];
  }
#pragma unroll
  for (int r = 0; r < 4; r++) {
    float s1 = 0.f, s2 = 0.f;
#pragma unroll
    for (int nt = 0; nt < 8; nt++) { float v = vals[nt][r]; s1 += v; s2 += v * v; }
#pragma unroll
    for (int m = 1; m < 16; m <<= 1) { s1 += __shfl_xor(s1, m); s2 += __shfl_xor(s2, m); }
    float mean = s1 * (1.f / 128.f);
    float inv = rsqrtf(s2 * (1.f / 128.f) - mean * mean + 1e-6f);
    size_t row = (tok0 + kg * 4 + r) * 128;
#pragma unroll
    for (int nt = 0; nt < 8; nt++) {
      int col = nt * 16 + col15;
      float v = vals[nt][r];
      X[row + col] = v;
      XB[row + col] = (short)f2b((v - mean) * inv * gv[nt] + bv[nt]);
    }
  }
}

// ---------------- MLP stage 1: H = relu(XB @ W1 + b1), persistent -----------
__global__ __launch_bounds__(256) void ff1_mfma(
    const short* __restrict__ XB, const short* __restrict__ W1t,
    const float* __restrict__ b1, short* __restrict__ H,
    int tokBase, int ntiles) {
  int wv = threadIdx.x >> 6, lane = threadIdx.x & 63;
  int col15 = lane & 15, kg = lane >> 4;
  bf16x8 w[8][4];
  float bias[8];
#pragma unroll
  for (int i = 0; i < 8; i++) {
    int col = wv * 128 + i * 16 + col15;
#pragma unroll
    for (int ks = 0; ks < 4; ks++)
      w[i][ks] = ldg8(W1t + (size_t)col * 128 + ks * 32 + kg * 8);
    bias[i] = b1[col];
  }
  for (int t = blockIdx.x; t < ntiles; t += gridDim.x) {
    size_t gtok = (size_t)tokBase + (size_t)t * 16;
    size_t ltok = (size_t)t * 16;
    bf16x8 a[4];
#pragma unroll
    for (int ks = 0; ks < 4; ks++)
      a[ks] = ldg8(XB + (gtok + col15) * 128 + ks * 32 + kg * 8);
    f32x4 acc[8];
#pragma unroll
    for (int i = 0; i < 8; i++) acc[i] = (f32x4){0.f, 0.f, 0.f, 0.f};
#pragma unroll
    for (int i = 0; i < 8; i++)
#pragma unroll
      for (int ks = 0; ks < 4; ks++)
        acc[i] = MFMA(a[ks], w[i][ks], acc[i], 0, 0, 0);
#pragma unroll
    for (int i = 0; i < 8; i++) {
      int col = wv * 128 + i * 16 + col15;
#pragma unroll
      for (int r = 0; r < 4; r++)
        H[(ltok + kg * 4 + r) * 512 + col] = (short)f2b(fmaxf(acc[i][r] + bias[i], 0.f));
    }
  }
}

// ---------------- MLP stage 2: XB = bf16(H @ W2 + b2 + X), persistent -------
__global__ __launch_bounds__(256) void ff2_mfma(
    const short* __restrict__ H, const short* __restrict__ W2t,
    const float* __restrict__ b2, const float* __restrict__ X,
    short* __restrict__ XBo, int tokBase, int ntiles) {
  int wv = threadIdx.x >> 6, lane = threadIdx.x & 63;
  int col15 = lane & 15, kg = lane >> 4;
  bf16x8 w[2][16];
  float bias[2];
#pragma unroll
  for (int i = 0; i < 2; i++) {
    int col = (wv * 2 + i) * 16 + col15;
#pragma unroll
    for (int ks = 0; ks < 16; ks++)
      w[i][ks] = ldg8(W2t + (size_t)col * 512 + ks * 32 + kg * 8);
    bias[i] = b2[col];
  }
  for (int t = blockIdx.x; t < ntiles; t += gridDim.x) {
    size_t gtok = (size_t)tokBase + (size_t)t * 16;
    size_t ltok = (size_t)t * 16;
    bf16x8 hh[16];
#pragma unroll
    for (int ks = 0; ks < 16; ks++)
      hh[ks] = ldg8(H + (ltok + col15) * 512 + ks * 32 + kg * 8);
    f32x4 acc[2];
#pragma unroll
    for (int i = 0; i < 2; i++) acc[i] = (f32x4){0.f, 0.f, 0.f, 0.f};
#pragma unroll
    for (int i = 0; i < 2; i++)
#pragma unroll
      for (int ks = 0; ks < 16; ks++)
        acc[i] = MFMA(hh[ks], w[i][ks], acc[i], 0, 0, 0);
#pragma unroll
    for (int i = 0; i < 2; i++) {
      int col = (wv * 2 + i) * 16 + col15;
#pragma unroll
      for (int r = 0; r < 4; r++) {
        size_t idx = (gtok + kg * 4 + r) * 128 + col;
        XBo[idx] = (short)f2b(X[idx] + acc[i][r] + bias[i]);
      }
    }
  }
}

// ---------------- fused un-partition + reverse projection (all levels) -------
// uniform 16-row x 32-col wave-tiles; wave-tile order: L3, L2, L1, L0
struct RevArgs {
  const short* wt[4];
  const float* bias[4];
  float* out[4];
  int hsS[4]; int wsS[4]; int tokOff[4];
  int chShift[4];   // log2 CHout
  int ntcShift[4];  // log2(CHout/32)
};
__global__ __launch_bounds__(256) void rev_all(RevArgs A, const short* __restrict__ XB) {
  int g = blockIdx.x * 4 + (threadIdx.x >> 6);
  int lane = threadIdx.x & 63, col15 = lane & 15, kg = lane >> 4;
  int lvl, lb;
  if (g < 2048) { lvl = 3; lb = g; }
  else if (g < 6144) { lvl = 2; lb = g - 2048; }
  else if (g < 14336) { lvl = 1; lb = g - 6144; }
  else { lvl = 0; lb = g - 14336; }
  int ntcS = A.ntcShift[lvl];
  int tr = lb >> ntcS, tc = lb & ((1 << ntcS) - 1);
  int CHout = 1 << A.chShift[lvl];
  int p0 = tr * 16, c0 = tc * 32;
  int atok = tokmap(p0 + col15, A.hsS[lvl], A.wsS[lvl], A.tokOff[lvl]);
  const short* abase = XB + (size_t)atok * 128 + kg * 8;
  bf16x8 a[4];
#pragma unroll
  for (int ks = 0; ks < 4; ks++) a[ks] = ldg8(abase + ks * 32);
  const short* Wt = A.wt[lvl];
  const float* bias = A.bias[lvl];
  float* out = A.out[lvl];
  size_t orow[4];
#pragma unroll
  for (int r = 0; r < 4; r++) orow[r] = (size_t)(p0 + kg * 4 + r) * CHout;
#pragma unroll
  for (int i = 0; i < 2; i++) {
    int col = c0 + i * 16 + col15;
    const short* bbase = Wt + (size_t)col * 128 + kg * 8;
    f32x4 c = (f32x4){0.f, 0.f, 0.f, 0.f};
#pragma unroll
    for (int ks = 0; ks < 4; ks++) c = MFMA(a[ks], ldg8(bbase + ks * 32), c, 0, 0, 0);
    float bb = bias[col];
#pragma unroll
    for (int r = 0; r < 4; r++) out[orow[r] + col] = c[r] + bb;
  }
}

extern "C" void kernel_launch(void* const* d_in, const int* in_sizes, int n_in,
                              void* d_out, int out_size, void* d_ws, size_t ws_size,
                              hipStream_t stream) {
  const float* x[4]; const float* fcW[4]; const float* fcb[4];
  const float* revW[4]; const float* revb[4];
  for (int j = 0; j < 4; j++) {
    x[j]    = (const float*)d_in[j * 5 + 0];
    fcW[j]  = (const float*)d_in[j * 5 + 1];
    fcb[j]  = (const float*)d_in[j * 5 + 2];
    revW[j] = (const float*)d_in[j * 5 + 3];
    revb[j] = (const float*)d_in[j * 5 + 4];
  }
  const float* ln1g = (const float*)d_in[20];
  const float* ln1b = (const float*)d_in[21];
  const float* ln2g = (const float*)d_in[22];
  const float* ln2b = (const float*)d_in[23];
  const float* qkvW = (const float*)d_in[24];
  const float* projW = (const float*)d_in[25];
  const float* fc1W = (const float*)d_in[26];
  const float* fc1b = (const float*)d_in[27];
  const float* fc2W = (const float*)d_in[28];
  const float* fc2b = (const float*)d_in[29];

  // workspace layout
  float* X    = (float*)d_ws;                           // NTOK*128 f32
  short* QKVH = (short*)(X + (size_t)NTOK * 128);       // NTOK*384 bf16 (head-major)
  short* XB   = QKVH + (size_t)NTOK * 384;              // NTOK*128 bf16
  short* ATB  = XB + (size_t)NTOK * 128;                // NTOK*128 bf16
  short* XIN  = ATB + (size_t)NTOK * 128;               // 15728640 bf16
  short* WT   = XIN + (size_t)15728640;                 // 688128 bf16
  short* H    = ATB;  // MLP hidden slab reuses dead ATB+XIN region

  static const int CH[4] = {128, 256, 512, 1024};
  static const int hsS[4] = {6, 5, 4, 3};
  static const int wsS[4] = {3, 2, 1, 0};
  static const int tokOff[4] = {0, 64, 80, 84};
  static const int chShift[4] = {7, 8, 9, 10};
  static const int xinOff[5] = {0, 8388608, 12582912, 14680064, 15728640};
  static const int fcWtOff[4] = {0, 16384, 49152, 114688};
  static const int revWtOff[4] = {245760, 262144, 294912, 360448};
  const int qkvWtOff = 491520, projWtOff = 540672, fc1WtOff = 557056, fc2WtOff = 622592;

  CvtX cx;
  for (int j = 0; j < 4; j++) { cx.src[j] = x[j]; cx.dst[j] = XIN + xinOff[j]; }
  for (int j = 0; j < 5; j++) cx.off[j] = xinOff[j];
  cvt_x_kernel<<<15360, 256, 0, stream>>>(cx);

  PrepW pw;
  int cum = 0;
  auto setw = [&](int idx, const float* src, short* dst, int K, int N) {
    pw.src[idx] = src; pw.dst[idx] = dst;
    int ksh = 0; while ((1 << ksh) < K) ksh++;
    pw.kshift[idx] = ksh; pw.N[idx] = N;
    pw.off[idx] = cum; cum += K * N;
  };
  for (int j = 0; j < 4; j++) setw(j, fcW[j], WT + fcWtOff[j], CH[j], 128);
  for (int j = 0; j < 4; j++) setw(4 + j, revW[j], WT + revWtOff[j], 128, CH[j]);
  setw(8, qkvW, WT + qkvWtOff, 128, 384);
  setw(9, projW, WT + projWtOff, 128, 128);
  setw(10, fc1W, WT + fc1WtOff, 128, 512);
  setw(11, fc2W, WT + fc2WtOff, 512, 128);
  pw.off[12] = cum;
  prep_w_kernel<<<2688, 256, 0, stream>>>(pw);

  // fused fc: [L3:64][L2:256][L1:256][L0:1024] = 1600 blocks
  FcAllArgs fa;
  for (int j = 0; j < 4; j++) {
    fa.xin[j] = XIN + xinOff[j];
    fa.wt[j] = WT + fcWtOff[j];
    fa.bias[j] = fcb[j];
    fa.hsS[j] = hsS[j]; fa.wsS[j] = wsS[j];
    fa.tokOff[j] = tokOff[j]; fa.chShift[j] = chShift[j];
  }
  fc_all<<<1600, 256, 0, stream>>>(fa, ln1g, ln1b, X, XB);

  qkv_mfma<<<1024, 256, 0, stream>>>(XB, WT + qkvWtOff, QKVH, NTOK / 32);
  attn_mfma<<<1024 * 8, 64, 0, stream>>>(QKVH, ATB);
  proj_mfma<<<NTOK / 64, 256, 0, stream>>>(ATB, WT + projWtOff, ln2g, ln2b, X, XB);
  // MLP in 2 token slabs of 43520 (H buffer reuses dead ATB+XIN region)
  ff1_mfma<<<1024, 256, 0, stream>>>(XB, WT + fc1WtOff, fc1b, H, 0, 2720);
  ff2_mfma<<<1024, 256, 0, stream>>>(H, WT + fc2WtOff, fc2b, X, XB, 0, 2720);
  ff1_mfma<<<1024, 256, 0, stream>>>(XB, WT + fc1WtOff, fc1b, H, 43520, 2720);
  ff2_mfma<<<1024, 256, 0, stream>>>(H, WT + fc2WtOff, fc2b, X, XB, 43520, 2720);

  // fused rev: 30720 wave-tiles (L3 first), 4 per block
  RevArgs ra;
  float* out = (float*)d_out;
  static const size_t outOffArr[4] = {0, 8388608, 12582912, 14680064};
  static const int ntcShift[4] = {2, 3, 4, 5};
  for (int j = 0; j < 4; j++) {
    ra.wt[j] = WT + revWtOff[j];
    ra.bias[j] = revb[j];
    ra.out[j] = out + outOffArr[j];
    ra.hsS[j] = hsS[j]; ra.wsS[j] = wsS[j]; ra.tokOff[j] = tokOff[j];
    ra.chShift[j] = chShift[j]; ra.ntcShift[j] = ntcShift[j];
  }
  rev_all<<<7680, 256, 0, stream>>>(ra, XB);
}